// Round 1
// baseline (7267.213 us; speedup 1.0000x reference)
//
#include <hip/hip_runtime.h>
#include <math.h>

// ---------------------------------------------------------------------------
// IG_RGCN forward on MI355X. Round 0: correctness-first fp32 baseline.
//   feat0 = [x@embed_w+b | tss[src0] | rs[src0]]            (N0 x 256)
//   per relation r: scatter (sum/max/deg) -> fc2(virtual concat) , fc1(dst),
//                   relu-concat -> fc3 -> z[r]
//   semantic attention (mean over nodes of tanh(z@w1+b1)@w2 -> softmax beta)
//   layer1: h1=relu(sum beta*z), feat1=[h1|tss[src1]|rs[src1]]
//   layer2: h2=sum beta*z2, out=sigmoid(h2@pred_w+pred_b)
// Workspace peak ~195 MB (feat1 aliases feat0, z2 aliases z1).
// ---------------------------------------------------------------------------

__device__ __forceinline__ void atomicMaxF(float* addr, float val) {
  if (val >= 0.f) atomicMax((int*)addr, __float_as_int(val));
  else            atomicMin((unsigned int*)addr, __float_as_uint(val));
}

// C[M,128] = act(A[M,K] @ W[K,128] + bias).  mode==1: A is the virtual
// fc2 input [aggM | aggS*invdeg | aggS] (K=768), row stride 256 per segment.
__global__ __launch_bounds__(256) void gemm_f32(
    const float* __restrict__ A, int lda,
    const float* __restrict__ W, const float* __restrict__ bias,
    float* __restrict__ C, int ldc, int M, int K, int relu,
    const float* __restrict__ aggM, const float* __restrict__ aggS,
    const float* __restrict__ invdeg, int mode)
{
  __shared__ float As[128][33];   // [row][k], +1 pad: conflict-free scalar reads
  __shared__ float Ws[32][128];   // [k][col]
  const int tid = threadIdx.x;
  const int tr = tid >> 4, tc = tid & 15;   // 16x16 thread grid, 8x8 each
  const int rowBase = blockIdx.x * 128;

  float acc[8][8];
  #pragma unroll
  for (int r = 0; r < 8; ++r)
    #pragma unroll
    for (int c = 0; c < 8; ++c) acc[r][c] = 0.f;

  for (int k0 = 0; k0 < K; k0 += 32) {
    __syncthreads();
    #pragma unroll
    for (int i = 0; i < 4; ++i) {          // A tile: 128 rows x 32 k
      int q = tid + 256 * i;               // 1024 float4s
      int row = q >> 3, kq = q & 7;
      int grow = rowBase + row;
      float4 v = make_float4(0.f, 0.f, 0.f, 0.f);
      if (grow < M) {
        int j = k0 + kq * 4;
        if (mode == 0) {
          v = *(const float4*)(A + (size_t)grow * lda + j);
        } else {
          int seg = j >> 8, jj = j & 255;
          if (seg == 0) v = *(const float4*)(aggM + (size_t)grow * 256 + jj);
          else {
            v = *(const float4*)(aggS + (size_t)grow * 256 + jj);
            if (seg == 1) { float s = invdeg[grow]; v.x*=s; v.y*=s; v.z*=s; v.w*=s; }
          }
        }
      }
      int kk = kq * 4;
      As[row][kk]   = v.x; As[row][kk+1] = v.y;
      As[row][kk+2] = v.z; As[row][kk+3] = v.w;
    }
    #pragma unroll
    for (int i = 0; i < 4; ++i) {          // W tile: 32 k x 128 col
      int q = tid + 256 * i;
      int kk = q >> 5, cc = (q & 31) * 4;
      *(float4*)&Ws[kk][cc] = *(const float4*)(W + (size_t)(k0 + kk) * 128 + cc);
    }
    __syncthreads();
    #pragma unroll 4
    for (int k = 0; k < 32; ++k) {
      float a[8], wv[8];
      #pragma unroll
      for (int r = 0; r < 8; ++r) a[r] = As[tr*8 + r][k];
      *(float4*)&wv[0] = *(float4*)&Ws[k][tc*8];
      *(float4*)&wv[4] = *(float4*)&Ws[k][tc*8 + 4];
      #pragma unroll
      for (int r = 0; r < 8; ++r)
        #pragma unroll
        for (int c = 0; c < 8; ++c)
          acc[r][c] = fmaf(a[r], wv[c], acc[r][c]);
    }
  }

  #pragma unroll
  for (int r = 0; r < 8; ++r) {
    int grow = rowBase + tr*8 + r;
    if (grow >= M) break;
    #pragma unroll
    for (int c = 0; c < 8; c += 4) {
      int col = tc*8 + c;
      float4 o;
      o.x = acc[r][c]   + bias[col];
      o.y = acc[r][c+1] + bias[col+1];
      o.z = acc[r][c+2] + bias[col+2];
      o.w = acc[r][c+3] + bias[col+3];
      if (relu) { o.x=fmaxf(o.x,0.f); o.y=fmaxf(o.y,0.f); o.z=fmaxf(o.z,0.f); o.w=fmaxf(o.w,0.f); }
      *(float4*)(C + (size_t)grow * ldc + col) = o;
    }
  }
}

// feat0 columns 128..255 <- tss[nid] | rs[nid]
__global__ void gather0_kernel(const float* __restrict__ tss, const float* __restrict__ rs,
                               const int* __restrict__ nid, int N, float* __restrict__ feat)
{
  int gid = blockIdx.x * blockDim.x + threadIdx.x;  // over N*32 float4
  if (gid >= N * 32) return;
  int n = gid >> 5, q = gid & 31;
  int id = nid[n];
  float4 v = (q < 16) ? *(const float4*)(tss + (size_t)id * 64 + q * 4)
                      : *(const float4*)(rs  + (size_t)id * 64 + (q - 16) * 4);
  *(float4*)(feat + (size_t)n * 256 + 128 + q * 4) = v;
}

__global__ void init_agg(float* __restrict__ aggS, float* __restrict__ aggM,
                         float* __restrict__ deg, int N)
{
  int i = blockIdx.x * blockDim.x + threadIdx.x;
  if (i < N * 256) { aggS[i] = 0.f; aggM[i] = -INFINITY; }
  if (i < N) deg[i] = 0.f;
}

__global__ void scatter_kernel(const float* __restrict__ feat,
                               const int* __restrict__ esrc, const int* __restrict__ edst,
                               int E, float* __restrict__ aggS, float* __restrict__ aggM,
                               float* __restrict__ deg)
{
  int gid = blockIdx.x * blockDim.x + threadIdx.x;  // E*64 threads (float4 chunks)
  if (gid >= E * 64) return;
  int e = gid >> 6, j = gid & 63;
  int s = esrc[e], d = edst[e];
  float4 v = *(const float4*)(feat + (size_t)s * 256 + j * 4);
  float* ps = aggS + (size_t)d * 256 + j * 4;
  atomicAdd(ps,   v.x); atomicAdd(ps+1, v.y);
  atomicAdd(ps+2, v.z); atomicAdd(ps+3, v.w);
  float* pm = aggM + (size_t)d * 256 + j * 4;
  atomicMaxF(pm,   v.x); atomicMaxF(pm+1, v.y);
  atomicMaxF(pm+2, v.z); atomicMaxF(pm+3, v.w);
  if (j == 0) atomicAdd(deg + d, 1.0f);
}

__global__ void finalize_agg(float* __restrict__ aggM, const float* __restrict__ deg,
                             float* __restrict__ invdeg, int N)
{
  int i = blockIdx.x * blockDim.x + threadIdx.x;
  if (i < N) invdeg[i] = 1.f / fmaxf(deg[i], 1.f);
  if (i < N * 256 && deg[i >> 8] == 0.f) aggM[i] = 0.f;  // DGL: zeros for isolated dst
}

// wsum[r] += sum_n tanh(z[r][n]@w1 + b1) @ w2   (32 nodes per block)
__global__ __launch_bounds__(256) void attn_stat(
    const float* __restrict__ z, const float* __restrict__ w1,
    const float* __restrict__ b1, const float* __restrict__ w2,
    int N, float* __restrict__ wsum)
{
  int r = blockIdx.y;
  int nb = blockIdx.x * 32;
  const float* zr = z + (size_t)r * N * 128;
  __shared__ float zl[32][128];
  #pragma unroll
  for (int i = 0; i < 4; ++i) {
    int q = threadIdx.x + 256 * i;           // 1024 float4
    int row = q >> 5, c4 = (q & 31) * 4;
    float4 v = make_float4(0.f, 0.f, 0.f, 0.f);
    if (nb + row < N) v = *(const float4*)(zr + (size_t)(nb + row) * 128 + c4);
    *(float4*)&zl[row][c4] = v;
  }
  __syncthreads();
  int col = threadIdx.x & 127, ng = threadIdx.x >> 7;
  float acc[16];
  #pragma unroll
  for (int n = 0; n < 16; ++n) acc[n] = 0.f;
  for (int k = 0; k < 128; ++k) {
    float wv = w1[k * 128 + col];
    #pragma unroll
    for (int n = 0; n < 16; ++n) acc[n] = fmaf(zl[ng*16 + n][k], wv, acc[n]);
  }
  float w2v = w2[col], b1v = b1[col];
  float local = 0.f;
  #pragma unroll
  for (int n = 0; n < 16; ++n)
    if (nb + ng*16 + n < N) local += tanhf(acc[n] + b1v) * w2v;
  #pragma unroll
  for (int o = 32; o > 0; o >>= 1) local += __shfl_down(local, o);
  __shared__ float red[4];
  if ((threadIdx.x & 63) == 0) red[threadIdx.x >> 6] = local;
  __syncthreads();
  if (threadIdx.x == 0) atomicAdd(&wsum[r], red[0] + red[1] + red[2] + red[3]);
}

__global__ void zero3(float* p) { if (threadIdx.x < 3) p[threadIdx.x] = 0.f; }

__global__ void beta_kernel(const float* __restrict__ wsum, float invN, float* __restrict__ beta) {
  float w0 = wsum[0] * invN, w1 = wsum[1] * invN, w2 = wsum[2] * invN;
  float m  = fmaxf(w0, fmaxf(w1, w2));
  float e0 = expf(w0 - m), e1 = expf(w1 - m), e2 = expf(w2 - m);
  float s  = e0 + e1 + e2;
  beta[0] = e0 / s; beta[1] = e1 / s; beta[2] = e2 / s;
}

// feat1 = [relu(sum_r beta[r]*z1[r]) | tss[nid] | rs[nid]]
__global__ __launch_bounds__(256) void combine1_kernel(
    const float* __restrict__ z1, const float* __restrict__ beta,
    const float* __restrict__ tss, const float* __restrict__ rs,
    const int* __restrict__ nid, int N, float* __restrict__ feat1)
{
  int n = blockIdx.x, t = threadIdx.x;
  size_t NH = (size_t)N * 128;
  if (t < 128) {
    float v = beta[0] * z1[(size_t)n*128 + t] + beta[1] * z1[NH + (size_t)n*128 + t]
            + beta[2] * z1[2*NH + (size_t)n*128 + t];
    feat1[(size_t)n*256 + t] = fmaxf(v, 0.f);
  } else {
    int j = t - 128;
    int id = nid[n];
    float v = (j < 64) ? tss[(size_t)id*64 + j] : rs[(size_t)id*64 + j - 64];
    feat1[(size_t)n*256 + t] = v;
  }
}

// out[n] = sigmoid( (sum_r beta[r]*z2[r][n]) @ pred_w + pred_b )
__global__ __launch_bounds__(128) void combine2_pred(
    const float* __restrict__ z2, const float* __restrict__ beta, int N,
    const float* __restrict__ pw, const float* __restrict__ pb, float* __restrict__ out)
{
  int n = blockIdx.x, t = threadIdx.x;
  size_t NH = (size_t)N * 128;
  float h = beta[0] * z2[(size_t)n*128 + t] + beta[1] * z2[NH + (size_t)n*128 + t]
          + beta[2] * z2[2*NH + (size_t)n*128 + t];
  float p = h * pw[t];
  #pragma unroll
  for (int o = 32; o > 0; o >>= 1) p += __shfl_down(p, o);
  __shared__ float red[2];
  if ((t & 63) == 0) red[t >> 6] = p;
  __syncthreads();
  if (t == 0) {
    float v = red[0] + red[1] + pb[0];
    out[n] = 1.f / (1.f + expf(-v));
  }
}

extern "C" void kernel_launch(void* const* d_in, const int* in_sizes, int n_in,
                              void* d_out, int out_size, void* d_ws, size_t ws_size,
                              hipStream_t stream)
{
  const float* x_user  = (const float*)d_in[0];
  const float* tss     = (const float*)d_in[1];
  const float* rs      = (const float*)d_in[2];
  const int* src_nid0  = (const int*)d_in[3];
  const int* src_nid1  = (const int*)d_in[4];
  const int* e0_src    = (const int*)d_in[5];
  const int* e0_dst    = (const int*)d_in[6];
  const int* e1_src    = (const int*)d_in[7];
  const int* e1_dst    = (const int*)d_in[8];
  const float* embed_w = (const float*)d_in[9];
  const float* embed_b = (const float*)d_in[10];
  const float* l1w[3]  = {(const float*)d_in[11], (const float*)d_in[13], (const float*)d_in[15]}; // fc1,fc2,fc3
  const float* l1b[3]  = {(const float*)d_in[12], (const float*)d_in[14], (const float*)d_in[16]};
  const float* l2w[3]  = {(const float*)d_in[17], (const float*)d_in[19], (const float*)d_in[21]};
  const float* l2b[3]  = {(const float*)d_in[18], (const float*)d_in[20], (const float*)d_in[22]};
  const float* attn_w1 = (const float*)d_in[23];
  const float* attn_b1 = (const float*)d_in[24];
  const float* attn_w2 = (const float*)d_in[25];
  const float* pred_w  = (const float*)d_in[26];
  const float* pred_b  = (const float*)d_in[27];
  float* out = (float*)d_out;

  const int N0 = in_sizes[0] / 128;
  const int N1 = in_sizes[4];
  const int N2 = out_size;
  const int E0 = in_sizes[5] / 3;
  const int E1 = in_sizes[7] / 3;

  char* wp = (char*)d_ws;
  auto walloc = [&](size_t bytes) {
    char* p = wp; wp += (bytes + 255) & ~(size_t)255; return p;
  };
  float* feat0  = (float*)walloc((size_t)N0 * 256 * 4);
  float* aggS   = (float*)walloc((size_t)N1 * 256 * 4);
  float* aggM   = (float*)walloc((size_t)N1 * 256 * 4);
  float* deg    = (float*)walloc((size_t)N1 * 4);
  float* invdeg = (float*)walloc((size_t)N1 * 4);
  float* inp    = (float*)walloc((size_t)N1 * 256 * 4);
  float* z1     = (float*)walloc((size_t)3 * N1 * 128 * 4);
  float* small  = (float*)walloc(256);
  float* wsum = small;
  float* beta = small + 4;
  float* feat1 = feat0;   // feat0 dead once conv1 finishes
  float* z2    = z1;      // z1 dead once attention-1 finishes
  (void)ws_size; (void)n_in;

  auto gemm = [&](const float* A, int lda, const float* W, const float* b, float* C,
                  int ldc, int M, int K, int relu,
                  const float* aM, const float* aS, const float* idg, int mode) {
    gemm_f32<<<dim3((M + 127) / 128), dim3(256), 0, stream>>>(
        A, lda, W, b, C, ldc, M, K, relu, aM, aS, idg, mode);
  };

  // ---- feat0 ----
  gemm(x_user, 128, embed_w, embed_b, feat0, 256, N0, 128, 0, nullptr, nullptr, nullptr, 0);
  gather0_kernel<<<(N0 * 32 + 255) / 256, 256, 0, stream>>>(tss, rs, src_nid0, N0, feat0);

  // ---- two conv layers ----
  for (int layer = 0; layer < 2; ++layer) {
    const float* featS = layer ? feat1 : feat0;
    int Nd = layer ? N2 : N1;
    int E  = layer ? E1 : E0;
    const int* es = layer ? e1_src : e0_src;
    const int* ed = layer ? e1_dst : e0_dst;
    const float* const* lw = layer ? l2w : l1w;
    const float* const* lb = layer ? l2b : l1b;
    float* z = layer ? z2 : z1;

    for (int r = 0; r < 3; ++r) {
      init_agg<<<(Nd * 256 + 255) / 256, 256, 0, stream>>>(aggS, aggM, deg, Nd);
      scatter_kernel<<<((size_t)E * 64 + 255) / 256, 256, 0, stream>>>(
          featS, es + (size_t)r * E, ed + (size_t)r * E, E, aggS, aggM, deg);
      finalize_agg<<<(Nd * 256 + 255) / 256, 256, 0, stream>>>(aggM, deg, invdeg, Nd);
      // fc2 on virtual [mx | mean | sum]  -> inp[:, 0:128], relu at store
      gemm(nullptr, 0, lw[1] + (size_t)r * 768 * 128, lb[1] + r * 128,
           inp, 256, Nd, 768, 1, aggM, aggS, invdeg, 1);
      // fc1 on dst feats -> inp[:, 128:256], relu at store
      gemm(featS, 256, lw[0] + (size_t)r * 256 * 128, lb[0] + r * 128,
           inp + 128, 256, Nd, 256, 1, nullptr, nullptr, nullptr, 0);
      // fc3 -> z[r]
      gemm(inp, 256, lw[2] + (size_t)r * 256 * 128, lb[2] + r * 128,
           z + (size_t)r * Nd * 128, 128, Nd, 256, 0, nullptr, nullptr, nullptr, 0);
    }

    zero3<<<1, 64, 0, stream>>>(wsum);
    attn_stat<<<dim3((Nd + 31) / 32, 3), 256, 0, stream>>>(z, attn_w1, attn_b1, attn_w2, Nd, wsum);
    beta_kernel<<<1, 1, 0, stream>>>(wsum, 1.0f / (float)Nd, beta);

    if (layer == 0) {
      combine1_kernel<<<N1, 256, 0, stream>>>(z1, beta, tss, rs, src_nid1, N1, feat1);
    } else {
      combine2_pred<<<N2, 128, 0, stream>>>(z2, beta, N2, pred_w, pred_b, out);
    }
  }
}

// Round 2
// 2132.468 us; speedup vs baseline: 3.4079x; 3.4079x over previous
//
#include <hip/hip_runtime.h>
#include <math.h>

// ---------------------------------------------------------------------------
// IG_RGCN forward on MI355X. Round 1: CSR-gather aggregation (no float
// atomics). Per relation: count-deg -> block scan -> fill CSR -> one wave
// per dst node gathers+reduces sum/max over its edge list.
// GEMMs unchanged fp32 register-tiled (Round-2 target).
// ---------------------------------------------------------------------------

// C[M,128] = act(A[M,K] @ W[K,128] + bias).  mode==1: A is the virtual
// fc2 input [aggM | aggS*invdeg | aggS] (K=768), row stride 256 per segment.
__global__ __launch_bounds__(256) void gemm_f32(
    const float* __restrict__ A, int lda,
    const float* __restrict__ W, const float* __restrict__ bias,
    float* __restrict__ C, int ldc, int M, int K, int relu,
    const float* __restrict__ aggM, const float* __restrict__ aggS,
    const float* __restrict__ invdeg, int mode)
{
  __shared__ float As[128][33];   // [row][k], +1 pad: conflict-free scalar reads
  __shared__ float Ws[32][128];   // [k][col]
  const int tid = threadIdx.x;
  const int tr = tid >> 4, tc = tid & 15;   // 16x16 thread grid, 8x8 each
  const int rowBase = blockIdx.x * 128;

  float acc[8][8];
  #pragma unroll
  for (int r = 0; r < 8; ++r)
    #pragma unroll
    for (int c = 0; c < 8; ++c) acc[r][c] = 0.f;

  for (int k0 = 0; k0 < K; k0 += 32) {
    __syncthreads();
    #pragma unroll
    for (int i = 0; i < 4; ++i) {          // A tile: 128 rows x 32 k
      int q = tid + 256 * i;               // 1024 float4s
      int row = q >> 3, kq = q & 7;
      int grow = rowBase + row;
      float4 v = make_float4(0.f, 0.f, 0.f, 0.f);
      if (grow < M) {
        int j = k0 + kq * 4;
        if (mode == 0) {
          v = *(const float4*)(A + (size_t)grow * lda + j);
        } else {
          int seg = j >> 8, jj = j & 255;
          if (seg == 0) v = *(const float4*)(aggM + (size_t)grow * 256 + jj);
          else {
            v = *(const float4*)(aggS + (size_t)grow * 256 + jj);
            if (seg == 1) { float s = invdeg[grow]; v.x*=s; v.y*=s; v.z*=s; v.w*=s; }
          }
        }
      }
      int kk = kq * 4;
      As[row][kk]   = v.x; As[row][kk+1] = v.y;
      As[row][kk+2] = v.z; As[row][kk+3] = v.w;
    }
    #pragma unroll
    for (int i = 0; i < 4; ++i) {          // W tile: 32 k x 128 col
      int q = tid + 256 * i;
      int kk = q >> 5, cc = (q & 31) * 4;
      *(float4*)&Ws[kk][cc] = *(const float4*)(W + (size_t)(k0 + kk) * 128 + cc);
    }
    __syncthreads();
    #pragma unroll 4
    for (int k = 0; k < 32; ++k) {
      float a[8], wv[8];
      #pragma unroll
      for (int r = 0; r < 8; ++r) a[r] = As[tr*8 + r][k];
      *(float4*)&wv[0] = *(float4*)&Ws[k][tc*8];
      *(float4*)&wv[4] = *(float4*)&Ws[k][tc*8 + 4];
      #pragma unroll
      for (int r = 0; r < 8; ++r)
        #pragma unroll
        for (int c = 0; c < 8; ++c)
          acc[r][c] = fmaf(a[r], wv[c], acc[r][c]);
    }
  }

  #pragma unroll
  for (int r = 0; r < 8; ++r) {
    int grow = rowBase + tr*8 + r;
    if (grow >= M) break;
    #pragma unroll
    for (int c = 0; c < 8; c += 4) {
      int col = tc*8 + c;
      float4 o;
      o.x = acc[r][c]   + bias[col];
      o.y = acc[r][c+1] + bias[col+1];
      o.z = acc[r][c+2] + bias[col+2];
      o.w = acc[r][c+3] + bias[col+3];
      if (relu) { o.x=fmaxf(o.x,0.f); o.y=fmaxf(o.y,0.f); o.z=fmaxf(o.z,0.f); o.w=fmaxf(o.w,0.f); }
      *(float4*)(C + (size_t)grow * ldc + col) = o;
    }
  }
}

// feat0 columns 128..255 <- tss[nid] | rs[nid]
__global__ void gather0_kernel(const float* __restrict__ tss, const float* __restrict__ rs,
                               const int* __restrict__ nid, int N, float* __restrict__ feat)
{
  int gid = blockIdx.x * blockDim.x + threadIdx.x;  // over N*32 float4
  if (gid >= N * 32) return;
  int n = gid >> 5, q = gid & 31;
  int id = nid[n];
  float4 v = (q < 16) ? *(const float4*)(tss + (size_t)id * 64 + q * 4)
                      : *(const float4*)(rs  + (size_t)id * 64 + (q - 16) * 4);
  *(float4*)(feat + (size_t)n * 256 + 128 + q * 4) = v;
}

// ---------------- CSR build ----------------
__global__ void zero_int(int* __restrict__ p, int n)
{
  int i = blockIdx.x * blockDim.x + threadIdx.x;
  if (i < n) p[i] = 0;
}

__global__ void count_deg(const int* __restrict__ edst, int E, int* __restrict__ deg)
{
  int e = blockIdx.x * blockDim.x + threadIdx.x;
  if (e < E) atomicAdd(&deg[edst[e]], 1);
}

// single-block hierarchical exclusive scan; also zeroes cursor
__global__ __launch_bounds__(1024) void scan_kernel(
    const int* __restrict__ deg, int* __restrict__ rowptr,
    int* __restrict__ cursor, int N)
{
  __shared__ int wtot[16];
  __shared__ int chunk_total_s;
  const int tid = threadIdx.x, lane = tid & 63, wid = tid >> 6;
  int running = 0;
  for (int base = 0; base < N; base += 1024) {
    int i = base + tid;
    int v = (i < N) ? deg[i] : 0;
    int incl = v;
    #pragma unroll
    for (int o = 1; o < 64; o <<= 1) {
      int t = __shfl_up(incl, o);
      if (lane >= o) incl += t;
    }
    if (lane == 63) wtot[wid] = incl;
    __syncthreads();
    if (wid == 0 && lane < 16) {
      int t = wtot[lane];
      int inc = t;
      #pragma unroll
      for (int o = 1; o < 16; o <<= 1) {
        int u = __shfl_up(inc, o);
        if (lane >= o) inc += u;
      }
      wtot[lane] = inc - t;               // exclusive wave offsets
      if (lane == 15) chunk_total_s = inc;
    }
    __syncthreads();
    int excl = running + wtot[wid] + (incl - v);
    if (i < N) { rowptr[i] = excl; cursor[i] = 0; }
    running += chunk_total_s;
    __syncthreads();                      // wtot reused next iteration
  }
  if (tid == 0) rowptr[N] = running;
}

__global__ void fill_csr(const int* __restrict__ esrc, const int* __restrict__ edst,
                         int E, const int* __restrict__ rowptr,
                         int* __restrict__ cursor, int* __restrict__ csr)
{
  int e = blockIdx.x * blockDim.x + threadIdx.x;
  if (e >= E) return;
  int d = edst[e];
  int pos = atomicAdd(&cursor[d], 1);
  csr[rowptr[d] + pos] = esrc[e];
}

// one wave per dst node: gather feat rows, reduce sum+max; write invdeg
__global__ __launch_bounds__(256) void agg_kernel(
    const float* __restrict__ feat, const int* __restrict__ csr,
    const int* __restrict__ rowptr, int N,
    float* __restrict__ aggS, float* __restrict__ aggM, float* __restrict__ invdeg)
{
  const int wid = threadIdx.x >> 6, lane = threadIdx.x & 63;
  const int node = blockIdx.x * 4 + wid;
  if (node >= N) return;
  const int start = rowptr[node], end = rowptr[node + 1];
  const int j = lane * 4;
  float4 s = make_float4(0.f, 0.f, 0.f, 0.f);
  float4 m = make_float4(-INFINITY, -INFINITY, -INFINITY, -INFINITY);
  for (int e = start; e < end; ++e) {
    int src = csr[e];                               // wave-broadcast load
    float4 v = *(const float4*)(feat + (size_t)src * 256 + j);
    s.x += v.x; s.y += v.y; s.z += v.z; s.w += v.w;
    m.x = fmaxf(m.x, v.x); m.y = fmaxf(m.y, v.y);
    m.z = fmaxf(m.z, v.z); m.w = fmaxf(m.w, v.w);
  }
  if (end == start) m = make_float4(0.f, 0.f, 0.f, 0.f);  // DGL isolated-dst zeros
  *(float4*)(aggS + (size_t)node * 256 + j) = s;
  *(float4*)(aggM + (size_t)node * 256 + j) = m;
  if (lane == 0) invdeg[node] = 1.f / fmaxf((float)(end - start), 1.f);
}

// ---------------- attention / combine ----------------
__global__ __launch_bounds__(256) void attn_stat(
    const float* __restrict__ z, const float* __restrict__ w1,
    const float* __restrict__ b1, const float* __restrict__ w2,
    int N, float* __restrict__ wsum)
{
  int r = blockIdx.y;
  int nb = blockIdx.x * 32;
  const float* zr = z + (size_t)r * N * 128;
  __shared__ float zl[32][128];
  #pragma unroll
  for (int i = 0; i < 4; ++i) {
    int q = threadIdx.x + 256 * i;           // 1024 float4
    int row = q >> 5, c4 = (q & 31) * 4;
    float4 v = make_float4(0.f, 0.f, 0.f, 0.f);
    if (nb + row < N) v = *(const float4*)(zr + (size_t)(nb + row) * 128 + c4);
    *(float4*)&zl[row][c4] = v;
  }
  __syncthreads();
  int col = threadIdx.x & 127, ng = threadIdx.x >> 7;
  float acc[16];
  #pragma unroll
  for (int n = 0; n < 16; ++n) acc[n] = 0.f;
  for (int k = 0; k < 128; ++k) {
    float wv = w1[k * 128 + col];
    #pragma unroll
    for (int n = 0; n < 16; ++n) acc[n] = fmaf(zl[ng*16 + n][k], wv, acc[n]);
  }
  float w2v = w2[col], b1v = b1[col];
  float local = 0.f;
  #pragma unroll
  for (int n = 0; n < 16; ++n)
    if (nb + ng*16 + n < N) local += tanhf(acc[n] + b1v) * w2v;
  #pragma unroll
  for (int o = 32; o > 0; o >>= 1) local += __shfl_down(local, o);
  __shared__ float red[4];
  if ((threadIdx.x & 63) == 0) red[threadIdx.x >> 6] = local;
  __syncthreads();
  if (threadIdx.x == 0) atomicAdd(&wsum[r], red[0] + red[1] + red[2] + red[3]);
}

__global__ void zero3(float* p) { if (threadIdx.x < 3) p[threadIdx.x] = 0.f; }

__global__ void beta_kernel(const float* __restrict__ wsum, float invN, float* __restrict__ beta) {
  float w0 = wsum[0] * invN, w1 = wsum[1] * invN, w2 = wsum[2] * invN;
  float m  = fmaxf(w0, fmaxf(w1, w2));
  float e0 = expf(w0 - m), e1 = expf(w1 - m), e2 = expf(w2 - m);
  float s  = e0 + e1 + e2;
  beta[0] = e0 / s; beta[1] = e1 / s; beta[2] = e2 / s;
}

// feat1 = [relu(sum_r beta[r]*z1[r]) | tss[nid] | rs[nid]]
__global__ __launch_bounds__(256) void combine1_kernel(
    const float* __restrict__ z1, const float* __restrict__ beta,
    const float* __restrict__ tss, const float* __restrict__ rs,
    const int* __restrict__ nid, int N, float* __restrict__ feat1)
{
  int n = blockIdx.x, t = threadIdx.x;
  size_t NH = (size_t)N * 128;
  if (t < 128) {
    float v = beta[0] * z1[(size_t)n*128 + t] + beta[1] * z1[NH + (size_t)n*128 + t]
            + beta[2] * z1[2*NH + (size_t)n*128 + t];
    feat1[(size_t)n*256 + t] = fmaxf(v, 0.f);
  } else {
    int j = t - 128;
    int id = nid[n];
    float v = (j < 64) ? tss[(size_t)id*64 + j] : rs[(size_t)id*64 + j - 64];
    feat1[(size_t)n*256 + t] = v;
  }
}

// out[n] = sigmoid( (sum_r beta[r]*z2[r][n]) @ pred_w + pred_b )
__global__ __launch_bounds__(128) void combine2_pred(
    const float* __restrict__ z2, const float* __restrict__ beta, int N,
    const float* __restrict__ pw, const float* __restrict__ pb, float* __restrict__ out)
{
  int n = blockIdx.x, t = threadIdx.x;
  size_t NH = (size_t)N * 128;
  float h = beta[0] * z2[(size_t)n*128 + t] + beta[1] * z2[NH + (size_t)n*128 + t]
          + beta[2] * z2[2*NH + (size_t)n*128 + t];
  float p = h * pw[t];
  #pragma unroll
  for (int o = 32; o > 0; o >>= 1) p += __shfl_down(p, o);
  __shared__ float red[2];
  if ((t & 63) == 0) red[t >> 6] = p;
  __syncthreads();
  if (t == 0) {
    float v = red[0] + red[1] + pb[0];
    out[n] = 1.f / (1.f + expf(-v));
  }
}

extern "C" void kernel_launch(void* const* d_in, const int* in_sizes, int n_in,
                              void* d_out, int out_size, void* d_ws, size_t ws_size,
                              hipStream_t stream)
{
  const float* x_user  = (const float*)d_in[0];
  const float* tss     = (const float*)d_in[1];
  const float* rs      = (const float*)d_in[2];
  const int* src_nid0  = (const int*)d_in[3];
  const int* src_nid1  = (const int*)d_in[4];
  const int* e0_src    = (const int*)d_in[5];
  const int* e0_dst    = (const int*)d_in[6];
  const int* e1_src    = (const int*)d_in[7];
  const int* e1_dst    = (const int*)d_in[8];
  const float* embed_w = (const float*)d_in[9];
  const float* embed_b = (const float*)d_in[10];
  const float* l1w[3]  = {(const float*)d_in[11], (const float*)d_in[13], (const float*)d_in[15]}; // fc1,fc2,fc3
  const float* l1b[3]  = {(const float*)d_in[12], (const float*)d_in[14], (const float*)d_in[16]};
  const float* l2w[3]  = {(const float*)d_in[17], (const float*)d_in[19], (const float*)d_in[21]};
  const float* l2b[3]  = {(const float*)d_in[18], (const float*)d_in[20], (const float*)d_in[22]};
  const float* attn_w1 = (const float*)d_in[23];
  const float* attn_b1 = (const float*)d_in[24];
  const float* attn_w2 = (const float*)d_in[25];
  const float* pred_w  = (const float*)d_in[26];
  const float* pred_b  = (const float*)d_in[27];
  float* out = (float*)d_out;

  const int N0 = in_sizes[0] / 128;
  const int N1 = in_sizes[4];
  const int N2 = out_size;
  const int E0 = in_sizes[5] / 3;
  const int E1 = in_sizes[7] / 3;

  char* wp = (char*)d_ws;
  auto walloc = [&](size_t bytes) {
    char* p = wp; wp += (bytes + 255) & ~(size_t)255; return p;
  };
  float* feat0  = (float*)walloc((size_t)N0 * 256 * 4);
  float* aggS   = (float*)walloc((size_t)N1 * 256 * 4);
  float* aggM   = (float*)walloc((size_t)N1 * 256 * 4);
  float* invdeg = (float*)walloc((size_t)N1 * 4);
  float* inp    = (float*)walloc((size_t)N1 * 256 * 4);
  float* z1     = (float*)walloc((size_t)3 * N1 * 128 * 4);
  int*   degcnt = (int*)walloc((size_t)N1 * 4);
  int*   rowptr = (int*)walloc((size_t)(N1 + 1) * 4);
  int*   csr    = (int*)walloc((size_t)E0 * 4);
  float* small  = (float*)walloc(256);
  float* wsum = small;
  float* beta = small + 4;
  float* feat1 = feat0;   // feat0 dead once conv1 finishes
  float* z2    = z1;      // z1 dead once attention-1 finishes
  (void)ws_size; (void)n_in;

  auto gemm = [&](const float* A, int lda, const float* W, const float* b, float* C,
                  int ldc, int M, int K, int relu,
                  const float* aM, const float* aS, const float* idg, int mode) {
    gemm_f32<<<dim3((M + 127) / 128), dim3(256), 0, stream>>>(
        A, lda, W, b, C, ldc, M, K, relu, aM, aS, idg, mode);
  };

  // ---- feat0 ----
  gemm(x_user, 128, embed_w, embed_b, feat0, 256, N0, 128, 0, nullptr, nullptr, nullptr, 0);
  gather0_kernel<<<(N0 * 32 + 255) / 256, 256, 0, stream>>>(tss, rs, src_nid0, N0, feat0);

  // ---- two conv layers ----
  for (int layer = 0; layer < 2; ++layer) {
    const float* featS = layer ? feat1 : feat0;
    int Nd = layer ? N2 : N1;
    int E  = layer ? E1 : E0;
    const int* es = layer ? e1_src : e0_src;
    const int* ed = layer ? e1_dst : e0_dst;
    const float* const* lw = layer ? l2w : l1w;
    const float* const* lb = layer ? l2b : l1b;
    float* z = layer ? z2 : z1;

    for (int r = 0; r < 3; ++r) {
      const int* esr = es + (size_t)r * E;
      const int* edr = ed + (size_t)r * E;
      // CSR build
      zero_int<<<(Nd + 255) / 256, 256, 0, stream>>>(degcnt, Nd);
      count_deg<<<(E + 255) / 256, 256, 0, stream>>>(edr, E, degcnt);
      scan_kernel<<<1, 1024, 0, stream>>>(degcnt, rowptr, degcnt /*cursor*/, Nd);
      fill_csr<<<(E + 255) / 256, 256, 0, stream>>>(esr, edr, E, rowptr, degcnt, csr);
      // gather-aggregate (sum, max, invdeg)
      agg_kernel<<<(Nd + 3) / 4, 256, 0, stream>>>(featS, csr, rowptr, Nd, aggS, aggM, invdeg);
      // fc2 on virtual [mx | mean | sum]  -> inp[:, 0:128], relu at store
      gemm(nullptr, 0, lw[1] + (size_t)r * 768 * 128, lb[1] + r * 128,
           inp, 256, Nd, 768, 1, aggM, aggS, invdeg, 1);
      // fc1 on dst feats -> inp[:, 128:256], relu at store
      gemm(featS, 256, lw[0] + (size_t)r * 256 * 128, lb[0] + r * 128,
           inp + 128, 256, Nd, 256, 1, nullptr, nullptr, nullptr, 0);
      // fc3 -> z[r]
      gemm(inp, 256, lw[2] + (size_t)r * 256 * 128, lb[2] + r * 128,
           z + (size_t)r * Nd * 128, 128, Nd, 256, 0, nullptr, nullptr, nullptr, 0);
    }

    zero3<<<1, 64, 0, stream>>>(wsum);
    attn_stat<<<dim3((Nd + 31) / 32, 3), 256, 0, stream>>>(z, attn_w1, attn_b1, attn_w2, Nd, wsum);
    beta_kernel<<<1, 1, 0, stream>>>(wsum, 1.0f / (float)Nd, beta);

    if (layer == 0) {
      combine1_kernel<<<N1, 256, 0, stream>>>(z1, beta, tss, rs, src_nid1, N1, feat1);
    } else {
      combine2_pred<<<N2, 128, 0, stream>>>(z2, beta, N2, pred_w, pred_b, out);
    }
  }
}

// Round 4
// 970.555 us; speedup vs baseline: 7.4877x; 2.1972x over previous
//
#include <hip/hip_runtime.h>
#include <math.h>

// ---------------------------------------------------------------------------
// IG_RGCN forward on MI355X. Round 3: Round-2 GEMMs + workspace-safe chunked
// aggregation (Round 2 overflowed d_ws: ~320 MB used vs ~195 MB proven).
//  - agg buffers hold CH dst-rows x 3 relations; CH chosen at runtime from
//    ws_size. Per chunk: agg_kernel -> fused fc2+fc1 batched GEMM.
//  - z1/z2 aliased into feat0 tail (rows >= N1): feat0 dead by fc3 time,
//    combine1 writes only rows < N1.
//  - Fixed ws: feat0 102.4 + inp 61.4 + csr/misc ~2.7 = ~166.5 MB.
// ---------------------------------------------------------------------------

struct GemmDesc {
  const float* A; int lda; size_t aStride;          // per-relation A stride
  const float* W; size_t wStride;                   // per-relation weight stride
  const float* bias;                                // [R,128]
  float* C; int ldc; size_t cStride;
  int M, K, relu;
  const float* aggM; const float* aggS;             // mode1 virtual input (chunk-local)
  const float* invdeg; size_t aggStride; int invStride;
  int mode;
};

// one 64x128 tile of C = act(A@W + b); blockIdx.y = relation, .z = descriptor
__global__ __launch_bounds__(256) void gemm2(GemmDesc d0, GemmDesc d1)
{
  const GemmDesc d = blockIdx.z ? d1 : d0;
  const int r = blockIdx.y;
  const float* W = d.W + (size_t)r * d.wStride;
  const float* bias = d.bias + (size_t)r * 128;
  const float* A = d.A + (size_t)r * d.aStride;
  const float* aggM = d.aggM + (size_t)r * d.aggStride;
  const float* aggS = d.aggS + (size_t)r * d.aggStride;
  const float* invdeg = d.invdeg + (size_t)r * d.invStride;

  __shared__ float As[32][68];   // k-major: A-frag read is aligned b128 broadcast
  __shared__ float Ws[32][128];
  const int tid = threadIdx.x;
  const int tr = tid >> 4, tc = tid & 15;
  const int rowBase = blockIdx.x * 64;

  float acc[4][8];
  #pragma unroll
  for (int i = 0; i < 4; ++i)
    #pragma unroll
    for (int c = 0; c < 8; ++c) acc[i][c] = 0.f;

  for (int k0 = 0; k0 < d.K; k0 += 32) {
    __syncthreads();
    #pragma unroll
    for (int i = 0; i < 2; ++i) {          // A tile: 64 rows x 32 k (512 float4)
      int q = tid + 256 * i;
      int row = q >> 3, kq = q & 7;
      int grow = rowBase + row;
      float4 v = make_float4(0.f, 0.f, 0.f, 0.f);
      if (grow < d.M) {
        int j = k0 + kq * 4;
        if (d.mode == 0) {
          v = *(const float4*)(A + (size_t)grow * d.lda + j);
        } else {
          int seg = j >> 8, jj = j & 255;
          if (seg == 0) v = *(const float4*)(aggM + (size_t)grow * 256 + jj);
          else {
            v = *(const float4*)(aggS + (size_t)grow * 256 + jj);
            if (seg == 1) { float s = invdeg[grow]; v.x*=s; v.y*=s; v.z*=s; v.w*=s; }
          }
        }
      }
      int kk = kq * 4;
      As[kk  ][row] = v.x; As[kk+1][row] = v.y;
      As[kk+2][row] = v.z; As[kk+3][row] = v.w;
    }
    #pragma unroll
    for (int i = 0; i < 4; ++i) {          // W tile: 32 k x 128 col
      int q = tid + 256 * i;
      int kk = q >> 5, cc = (q & 31) * 4;
      *(float4*)&Ws[kk][cc] = *(const float4*)(W + (size_t)(k0 + kk) * 128 + cc);
    }
    __syncthreads();
    #pragma unroll 8
    for (int k = 0; k < 32; ++k) {
      float4 av = *(const float4*)&As[k][tr * 4];
      float4 w0 = *(const float4*)&Ws[k][tc * 4];
      float4 w1 = *(const float4*)&Ws[k][tc * 4 + 64];
      float ar[4] = {av.x, av.y, av.z, av.w};
      float wv[8] = {w0.x, w0.y, w0.z, w0.w, w1.x, w1.y, w1.z, w1.w};
      #pragma unroll
      for (int i = 0; i < 4; ++i)
        #pragma unroll
        for (int c = 0; c < 8; ++c)
          acc[i][c] = fmaf(ar[i], wv[c], acc[i][c]);
    }
  }

  const float4 b0 = *(const float4*)&bias[tc * 4];
  const float4 b1 = *(const float4*)&bias[tc * 4 + 64];
  float* Cr = d.C + (size_t)r * d.cStride;
  #pragma unroll
  for (int i = 0; i < 4; ++i) {
    int grow = rowBase + tr * 4 + i;
    if (grow >= d.M) break;
    float4 o0, o1;
    o0.x = acc[i][0] + b0.x; o0.y = acc[i][1] + b0.y;
    o0.z = acc[i][2] + b0.z; o0.w = acc[i][3] + b0.w;
    o1.x = acc[i][4] + b1.x; o1.y = acc[i][5] + b1.y;
    o1.z = acc[i][6] + b1.z; o1.w = acc[i][7] + b1.w;
    if (d.relu) {
      o0.x=fmaxf(o0.x,0.f); o0.y=fmaxf(o0.y,0.f); o0.z=fmaxf(o0.z,0.f); o0.w=fmaxf(o0.w,0.f);
      o1.x=fmaxf(o1.x,0.f); o1.y=fmaxf(o1.y,0.f); o1.z=fmaxf(o1.z,0.f); o1.w=fmaxf(o1.w,0.f);
    }
    *(float4*)(Cr + (size_t)grow * d.ldc + tc * 4)      = o0;
    *(float4*)(Cr + (size_t)grow * d.ldc + tc * 4 + 64) = o1;
  }
}

// feat0 columns 128..255 <- tss[nid] | rs[nid]
__global__ void gather0_kernel(const float* __restrict__ tss, const float* __restrict__ rs,
                               const int* __restrict__ nid, int N, float* __restrict__ feat)
{
  int gid = blockIdx.x * blockDim.x + threadIdx.x;
  if (gid >= N * 32) return;
  int n = gid >> 5, q = gid & 31;
  int id = nid[n];
  float4 v = (q < 16) ? *(const float4*)(tss + (size_t)id * 64 + q * 4)
                      : *(const float4*)(rs  + (size_t)id * 64 + (q - 16) * 4);
  *(float4*)(feat + (size_t)n * 256 + 128 + q * 4) = v;
}

// ---------------- CSR build (batched over R=3 relations) ----------------
__global__ void zero_int(int* __restrict__ p, int n)
{
  int i = blockIdx.x * blockDim.x + threadIdx.x;
  if (i < n) p[i] = 0;
}

__global__ void count_deg(const int* __restrict__ edst, int E, int N, int* __restrict__ deg)
{
  int e = blockIdx.x * blockDim.x + threadIdx.x;
  int r = blockIdx.y;
  if (e < E) atomicAdd(&deg[r * N + edst[(size_t)r * E + e]], 1);
}

// single-block hierarchical exclusive scan over N entries; zeroes cursor
__global__ __launch_bounds__(1024) void scan_kernel(
    const int* __restrict__ deg, int* __restrict__ rowptr,
    int* __restrict__ cursor, int N)
{
  __shared__ int wtot[16];
  __shared__ int chunk_total_s;
  const int tid = threadIdx.x, lane = tid & 63, wid = tid >> 6;
  int running = 0;
  for (int base = 0; base < N; base += 1024) {
    int i = base + tid;
    int v = (i < N) ? deg[i] : 0;
    int incl = v;
    #pragma unroll
    for (int o = 1; o < 64; o <<= 1) {
      int t = __shfl_up(incl, o);
      if (lane >= o) incl += t;
    }
    if (lane == 63) wtot[wid] = incl;
    __syncthreads();
    if (wid == 0 && lane < 16) {
      int t = wtot[lane];
      int inc = t;
      #pragma unroll
      for (int o = 1; o < 16; o <<= 1) {
        int u = __shfl_up(inc, o);
        if (lane >= o) inc += u;
      }
      wtot[lane] = inc - t;
      if (lane == 15) chunk_total_s = inc;
    }
    __syncthreads();
    int excl = running + wtot[wid] + (incl - v);
    if (i < N) { rowptr[i] = excl; cursor[i] = 0; }
    running += chunk_total_s;
    __syncthreads();
  }
  if (tid == 0) rowptr[N] = running;
}

__global__ void fill_csr(const int* __restrict__ esrc, const int* __restrict__ edst,
                         int E, int N, const int* __restrict__ rowptr,
                         int* __restrict__ cursor, int* __restrict__ csr)
{
  int e = blockIdx.x * blockDim.x + threadIdx.x;
  int r = blockIdx.y;
  if (e >= E) return;
  int d = r * N + edst[(size_t)r * E + e];
  int pos = atomicAdd(&cursor[d], 1);
  csr[rowptr[d] + pos] = esrc[(size_t)r * E + e];
}

// one wave per (relation, chunk-local dst node): gather + sum/max; chunk-local out
__global__ __launch_bounds__(256) void agg_kernel(
    const float* __restrict__ feat, const int* __restrict__ csr,
    const int* __restrict__ rowptr, int N, int c0, int cr, int CH,
    float* __restrict__ aggS, float* __restrict__ aggM, float* __restrict__ invdeg)
{
  const int wid = threadIdx.x >> 6, lane = threadIdx.x & 63;
  const int node = blockIdx.x * 4 + wid;         // chunk-local
  if (node >= cr) return;
  const int g = blockIdx.y * N + c0 + node;      // rowptr index
  const int o = blockIdx.y * CH + node;          // agg buffer index
  const int start = rowptr[g], end = rowptr[g + 1];
  const int j = lane * 4;
  float4 s = make_float4(0.f, 0.f, 0.f, 0.f);
  float4 m = make_float4(-INFINITY, -INFINITY, -INFINITY, -INFINITY);
  for (int e = start; e < end; ++e) {
    int src = csr[e];
    float4 v = *(const float4*)(feat + (size_t)src * 256 + j);
    s.x += v.x; s.y += v.y; s.z += v.z; s.w += v.w;
    m.x = fmaxf(m.x, v.x); m.y = fmaxf(m.y, v.y);
    m.z = fmaxf(m.z, v.z); m.w = fmaxf(m.w, v.w);
  }
  if (end == start) m = make_float4(0.f, 0.f, 0.f, 0.f);
  *(float4*)(aggS + (size_t)o * 256 + j) = s;
  *(float4*)(aggM + (size_t)o * 256 + j) = m;
  if (lane == 0) invdeg[o] = 1.f / fmaxf((float)(end - start), 1.f);
}

// ---------------- attention / combine ----------------
__global__ __launch_bounds__(256) void attn_stat(
    const float* __restrict__ z, const float* __restrict__ w1,
    const float* __restrict__ b1, const float* __restrict__ w2,
    int N, float* __restrict__ wsum)
{
  int r = blockIdx.y;
  int nb = blockIdx.x * 32;
  const float* zr = z + (size_t)r * N * 128;
  __shared__ float zl[32][128];
  #pragma unroll
  for (int i = 0; i < 4; ++i) {
    int q = threadIdx.x + 256 * i;
    int row = q >> 5, c4 = (q & 31) * 4;
    float4 v = make_float4(0.f, 0.f, 0.f, 0.f);
    if (nb + row < N) v = *(const float4*)(zr + (size_t)(nb + row) * 128 + c4);
    *(float4*)&zl[row][c4] = v;
  }
  __syncthreads();
  int col = threadIdx.x & 127, ng = threadIdx.x >> 7;
  float acc[16];
  #pragma unroll
  for (int n = 0; n < 16; ++n) acc[n] = 0.f;
  for (int k = 0; k < 128; ++k) {
    float wv = w1[k * 128 + col];
    #pragma unroll
    for (int n = 0; n < 16; ++n) acc[n] = fmaf(zl[ng*16 + n][k], wv, acc[n]);
  }
  float w2v = w2[col], b1v = b1[col];
  float local = 0.f;
  #pragma unroll
  for (int n = 0; n < 16; ++n)
    if (nb + ng*16 + n < N) local += tanhf(acc[n] + b1v) * w2v;
  #pragma unroll
  for (int o = 32; o > 0; o >>= 1) local += __shfl_down(local, o);
  __shared__ float red[4];
  if ((threadIdx.x & 63) == 0) red[threadIdx.x >> 6] = local;
  __syncthreads();
  if (threadIdx.x == 0) atomicAdd(&wsum[r], red[0] + red[1] + red[2] + red[3]);
}

__global__ void zero3(float* p) { if (threadIdx.x < 3) p[threadIdx.x] = 0.f; }

__global__ void beta_kernel(const float* __restrict__ wsum, float invN, float* __restrict__ beta) {
  float w0 = wsum[0] * invN, w1 = wsum[1] * invN, w2 = wsum[2] * invN;
  float m  = fmaxf(w0, fmaxf(w1, w2));
  float e0 = expf(w0 - m), e1 = expf(w1 - m), e2 = expf(w2 - m);
  float s  = e0 + e1 + e2;
  beta[0] = e0 / s; beta[1] = e1 / s; beta[2] = e2 / s;
}

__global__ __launch_bounds__(256) void combine1_kernel(
    const float* __restrict__ z1, const float* __restrict__ beta,
    const float* __restrict__ tss, const float* __restrict__ rs,
    const int* __restrict__ nid, int N, float* __restrict__ feat1)
{
  int n = blockIdx.x, t = threadIdx.x;
  size_t NH = (size_t)N * 128;
  if (t < 128) {
    float v = beta[0] * z1[(size_t)n*128 + t] + beta[1] * z1[NH + (size_t)n*128 + t]
            + beta[2] * z1[2*NH + (size_t)n*128 + t];
    feat1[(size_t)n*256 + t] = fmaxf(v, 0.f);
  } else {
    int j = t - 128;
    int id = nid[n];
    float v = (j < 64) ? tss[(size_t)id*64 + j] : rs[(size_t)id*64 + j - 64];
    feat1[(size_t)n*256 + t] = v;
  }
}

__global__ __launch_bounds__(128) void combine2_pred(
    const float* __restrict__ z2, const float* __restrict__ beta, int N,
    const float* __restrict__ pw, const float* __restrict__ pb, float* __restrict__ out)
{
  int n = blockIdx.x, t = threadIdx.x;
  size_t NH = (size_t)N * 128;
  float h = beta[0] * z2[(size_t)n*128 + t] + beta[1] * z2[NH + (size_t)n*128 + t]
          + beta[2] * z2[2*NH + (size_t)n*128 + t];
  float p = h * pw[t];
  #pragma unroll
  for (int o = 32; o > 0; o >>= 1) p += __shfl_down(p, o);
  __shared__ float red[2];
  if ((t & 63) == 0) red[t >> 6] = p;
  __syncthreads();
  if (t == 0) {
    float v = red[0] + red[1] + pb[0];
    out[n] = 1.f / (1.f + expf(-v));
  }
}

extern "C" void kernel_launch(void* const* d_in, const int* in_sizes, int n_in,
                              void* d_out, int out_size, void* d_ws, size_t ws_size,
                              hipStream_t stream)
{
  const float* x_user  = (const float*)d_in[0];
  const float* tss     = (const float*)d_in[1];
  const float* rs      = (const float*)d_in[2];
  const int* src_nid0  = (const int*)d_in[3];
  const int* src_nid1  = (const int*)d_in[4];
  const int* e0_src    = (const int*)d_in[5];
  const int* e0_dst    = (const int*)d_in[6];
  const int* e1_src    = (const int*)d_in[7];
  const int* e1_dst    = (const int*)d_in[8];
  const float* embed_w = (const float*)d_in[9];
  const float* embed_b = (const float*)d_in[10];
  const float* l1w[3]  = {(const float*)d_in[11], (const float*)d_in[13], (const float*)d_in[15]};
  const float* l1b[3]  = {(const float*)d_in[12], (const float*)d_in[14], (const float*)d_in[16]};
  const float* l2w[3]  = {(const float*)d_in[17], (const float*)d_in[19], (const float*)d_in[21]};
  const float* l2b[3]  = {(const float*)d_in[18], (const float*)d_in[20], (const float*)d_in[22]};
  const float* attn_w1 = (const float*)d_in[23];
  const float* attn_b1 = (const float*)d_in[24];
  const float* attn_w2 = (const float*)d_in[25];
  const float* pred_w  = (const float*)d_in[26];
  const float* pred_b  = (const float*)d_in[27];
  float* out = (float*)d_out;

  const int N0 = in_sizes[0] / 128;
  const int N1 = in_sizes[4];
  const int N2 = out_size;
  const int E0 = in_sizes[5] / 3;
  const int E1 = in_sizes[7] / 3;

  char* wp = (char*)d_ws;
  auto walloc = [&](size_t bytes) {
    char* p = wp; wp += (bytes + 255) & ~(size_t)255; return p;
  };
  // Fixed allocations (~166.5 MB)
  float* feat0  = (float*)walloc((size_t)N0 * 256 * 4);   // also hosts feat1 (rows<N1) + z (rows>=N1)
  float* inp    = (float*)walloc((size_t)3 * N1 * 256 * 4);
  int*   degcnt = (int*)walloc((size_t)3 * N1 * 4);
  int*   rowptr = (int*)walloc((size_t)(3 * N1 + 1) * 4);
  int*   csr    = (int*)walloc((size_t)3 * E0 * 4);
  float* small  = (float*)walloc(256);
  float* wsum = small;
  float* beta = small + 4;
  float* feat1 = feat0;                                   // rows 0..N1
  float* zbuf  = feat0 + (size_t)N1 * 256;                // z1/z2: feat0 dead by fc3

  // Adaptive agg chunk size from remaining workspace
  size_t used = (size_t)(wp - (char*)d_ws);
  size_t avail = (ws_size > used + 65536) ? (ws_size - used - 65536) : 0;
  const size_t per_row = (size_t)3 * (2 * 256 * 4 + 4 + 256); // aggS+aggM+invdeg (+align slop)
  int CH = (int)(avail / per_row);
  if (CH > N1) CH = N1;
  if (CH < 1024) CH = 1024;     // floor; below this ws was never viable anyway
  float* aggS   = (float*)walloc((size_t)3 * CH * 256 * 4);
  float* aggM   = (float*)walloc((size_t)3 * CH * 256 * 4);
  float* invdeg = (float*)walloc((size_t)3 * CH * 4);
  (void)n_in;

  GemmDesc dz = {};  // dummy for single-descriptor launches

  // ---- feat0 = [x@embed | tss | rs] ----
  {
    GemmDesc d = {x_user, 128, 0, embed_w, 0, embed_b, feat0, 256, 0,
                  N0, 128, 0, feat0, feat0, (const float*)small, 0, 0, 0};
    gemm2<<<dim3((N0 + 63) / 64, 1, 1), 256, 0, stream>>>(d, dz);
  }
  gather0_kernel<<<(N0 * 32 + 255) / 256, 256, 0, stream>>>(tss, rs, src_nid0, N0, feat0);

  // ---- two conv layers ----
  for (int layer = 0; layer < 2; ++layer) {
    const float* featS = layer ? feat1 : feat0;
    int Nd = layer ? N2 : N1;
    int E  = layer ? E1 : E0;
    const int* es = layer ? e1_src : e0_src;
    const int* ed = layer ? e1_dst : e0_dst;
    const float* const* lw = layer ? l2w : l1w;
    const float* const* lb = layer ? l2b : l1b;
    float* z = zbuf;

    // CSR build for all 3 relations
    zero_int<<<(3 * Nd + 255) / 256, 256, 0, stream>>>(degcnt, 3 * Nd);
    count_deg<<<dim3((E + 255) / 256, 3), 256, 0, stream>>>(ed, E, Nd, degcnt);
    scan_kernel<<<1, 1024, 0, stream>>>(degcnt, rowptr, degcnt, 3 * Nd);
    fill_csr<<<dim3((E + 255) / 256, 3), 256, 0, stream>>>(es, ed, E, Nd, rowptr, degcnt, csr);

    // chunked: agg -> fused fc2 (z=0, K=768 virtual) + fc1 (z=1, K=256)
    for (int c0 = 0; c0 < Nd; c0 += CH) {
      int cr = (Nd - c0 < CH) ? (Nd - c0) : CH;
      agg_kernel<<<dim3((cr + 3) / 4, 3), 256, 0, stream>>>(
          featS, csr, rowptr, Nd, c0, cr, CH, aggS, aggM, invdeg);
      GemmDesc d2 = {nullptr, 0, 0, lw[1], (size_t)768 * 128, lb[1],
                     inp + (size_t)c0 * 256, 256, (size_t)Nd * 256,
                     cr, 768, 1, aggM, aggS, invdeg, (size_t)CH * 256, CH, 1};
      GemmDesc d1 = {featS + (size_t)c0 * 256, 256, 0, lw[0], (size_t)256 * 128, lb[0],
                     inp + 128 + (size_t)c0 * 256, 256, (size_t)Nd * 256,
                     cr, 256, 1, aggM, aggS, invdeg, 0, 0, 0};
      gemm2<<<dim3((cr + 63) / 64, 3, 2), 256, 0, stream>>>(d2, d1);
    }
    // fc3 -> z (full batch over relations)
    {
      GemmDesc d3 = {inp, 256, (size_t)Nd * 256, lw[2], (size_t)256 * 128, lb[2],
                     z, 128, (size_t)Nd * 128, Nd, 256, 0,
                     aggM, aggS, invdeg, 0, 0, 0};
      gemm2<<<dim3((Nd + 63) / 64, 3, 1), 256, 0, stream>>>(d3, dz);
    }

    zero3<<<1, 64, 0, stream>>>(wsum);
    attn_stat<<<dim3((Nd + 31) / 32, 3), 256, 0, stream>>>(z, attn_w1, attn_b1, attn_w2, Nd, wsum);
    beta_kernel<<<1, 1, 0, stream>>>(wsum, 1.0f / (float)Nd, beta);

    if (layer == 0) {
      combine1_kernel<<<N1, 256, 0, stream>>>(z, beta, tss, rs, src_nid1, N1, feat1);
    } else {
      combine2_pred<<<N2, 128, 0, stream>>>(z, beta, N2, pred_w, pred_b, out);
    }
  }
}

// Round 5
// 674.088 us; speedup vs baseline: 10.7808x; 1.4398x over previous
//
#include <hip/hip_runtime.h>
#include <math.h>

// ---------------------------------------------------------------------------
// IG_RGCN forward on MI355X. Round 5: bf16 MFMA GEMMs + bf16 feature storage.
//  - gemm_mfma: 128x128 tile, BK=32, 4 waves, v_mfma_f32_16x16x32_bf16.
//    A staged fp32->bf16 / bf16 / virtual [mx|mean|sum]; W pre-transposed
//    to Wt[128 cols][K] bf16 once per call (~2 MB).
//  - feat0/feat1/inp/aggS/aggM stored bf16 (halves agg gather traffic);
//    z / bias / attention / predictor kept fp32.
//  - Error budget: bf16 rounding ~2^-9 rel, fp32 MFMA accum; predicted
//    output absmax ~3e-3 vs 1.24e-2 threshold.
// ---------------------------------------------------------------------------

typedef short s16x8 __attribute__((ext_vector_type(8)));
typedef float f32x4 __attribute__((ext_vector_type(4)));

__device__ __forceinline__ ushort f2bf(float f) {
  unsigned u = __float_as_uint(f);
  return (ushort)((u + 0x7FFFu + ((u >> 16) & 1u)) >> 16);
}
__device__ __forceinline__ float bf2f(unsigned hbits) {
  return __uint_as_float(hbits << 16);
}
__device__ __forceinline__ unsigned pack2(float lo, float hi) {
  return (unsigned)f2bf(lo) | ((unsigned)f2bf(hi) << 16);
}

// W[r][K][128] fp32 -> Wt[r][128][K] bf16
__global__ void prep_w(const float* __restrict__ W, ushort* __restrict__ Wt, int K)
{
  int k = blockIdx.x * 256 + threadIdx.x;
  int n = blockIdx.y;       // 0..127
  int r = blockIdx.z;
  if (k >= K) return;
  Wt[((size_t)r * 128 + n) * K + k] = f2bf(W[((size_t)r * K + k) * 128 + n]);
}

struct GemmDesc {
  const void* A; int lda; size_t aStride; int aKind;   // 0 fp32, 1 bf16, 2 virtual agg
  const ushort* Wt; size_t wStride;                    // [128][K] bf16 per relation
  const float* bias; int biasStride;
  void* C; int ldc; size_t cStride; int cKind;         // 0 fp32, 1 bf16
  int M, K, relu;
  const ushort* aggM; const ushort* aggS; const float* invdeg;
  size_t aggStride; int invStride;
};

// C[M,128] = act(A[M,K] @ W + b); blockIdx.y = relation, .z = descriptor
__global__ __launch_bounds__(256) void gemm_mfma(GemmDesc d0, GemmDesc d1)
{
  const GemmDesc d = blockIdx.z ? d1 : d0;
  const int r = blockIdx.y;
  __shared__ ushort As[128 * 32];   // row-major, row stride 32 (64 B)
  __shared__ ushort Bs[128 * 32];   // col-major: Bs[col*32 + k]

  const int tid = threadIdx.x;
  const int wave = tid >> 6, lane = tid & 63;
  const int m16 = lane & 15, quad = lane >> 4;
  const int rowBase = blockIdx.x * 128;
  const ushort* Wt = d.Wt + (size_t)r * d.wStride;

  f32x4 acc[2][8];
  #pragma unroll
  for (int i = 0; i < 2; ++i)
    #pragma unroll
    for (int j = 0; j < 8; ++j)
      #pragma unroll
      for (int p = 0; p < 4; ++p) acc[i][j][p] = 0.f;

  for (int k0 = 0; k0 < d.K; k0 += 32) {
    __syncthreads();
    if (d.aKind == 1) {                       // bf16 rows
      const ushort* Ab = (const ushort*)d.A + (size_t)r * d.aStride;
      #pragma unroll
      for (int i = 0; i < 2; ++i) {
        int q = tid + 256 * i;                // 512 chunks of 16 B
        int row = q >> 2, c = (q & 3) * 8;
        int grow = rowBase + row;
        uint4 v = make_uint4(0, 0, 0, 0);
        if (grow < d.M) v = *(const uint4*)(Ab + (size_t)grow * d.lda + k0 + c);
        *(uint4*)&As[row * 32 + c] = v;
      }
    } else if (d.aKind == 0) {                // fp32 rows, convert
      const float* Ab = (const float*)d.A + (size_t)r * d.aStride;
      #pragma unroll
      for (int i = 0; i < 4; ++i) {
        int q = tid + 256 * i;                // 1024 float4
        int row = q >> 3, c = (q & 7) * 4;
        int grow = rowBase + row;
        float4 f = make_float4(0.f, 0.f, 0.f, 0.f);
        if (grow < d.M) f = *(const float4*)(Ab + (size_t)grow * d.lda + k0 + c);
        uint2 pk; pk.x = pack2(f.x, f.y); pk.y = pack2(f.z, f.w);
        *(uint2*)&As[row * 32 + c] = pk;
      }
    } else {                                  // virtual [mx | sum*invdeg | sum]
      int seg = k0 >> 8, jj = k0 & 255;
      const ushort* Ab = (seg == 0 ? d.aggM : d.aggS) + (size_t)r * d.aggStride;
      const float* idg = d.invdeg + (size_t)r * d.invStride;
      #pragma unroll
      for (int i = 0; i < 2; ++i) {
        int q = tid + 256 * i;
        int row = q >> 2, c = (q & 3) * 8;
        int grow = rowBase + row;
        uint4 v = make_uint4(0, 0, 0, 0);
        if (grow < d.M) {
          v = *(const uint4*)(Ab + (size_t)grow * 256 + jj + c);
          if (seg == 1) {
            float s = idg[grow];
            v.x = pack2(bf2f(v.x & 0xFFFFu) * s, bf2f(v.x >> 16) * s);
            v.y = pack2(bf2f(v.y & 0xFFFFu) * s, bf2f(v.y >> 16) * s);
            v.z = pack2(bf2f(v.z & 0xFFFFu) * s, bf2f(v.z >> 16) * s);
            v.w = pack2(bf2f(v.w & 0xFFFFu) * s, bf2f(v.w >> 16) * s);
          }
        }
        *(uint4*)&As[row * 32 + c] = v;
      }
    }
    #pragma unroll
    for (int i = 0; i < 2; ++i) {             // B tile: 128 cols x 32 k
      int q = tid + 256 * i;
      int col = q >> 2, c = (q & 3) * 8;
      uint4 v = *(const uint4*)(Wt + (size_t)col * d.K + k0 + c);
      *(uint4*)&Bs[col * 32 + c] = v;
    }
    __syncthreads();

    s16x8 af[2], bfr[8];
    af[0] = *(const s16x8*)&As[(wave * 32 + m16) * 32 + quad * 8];
    af[1] = *(const s16x8*)&As[(wave * 32 + 16 + m16) * 32 + quad * 8];
    #pragma unroll
    for (int j = 0; j < 8; ++j)
      bfr[j] = *(const s16x8*)&Bs[(j * 16 + m16) * 32 + quad * 8];
    #pragma unroll
    for (int i = 0; i < 2; ++i)
      #pragma unroll
      for (int j = 0; j < 8; ++j)
        acc[i][j] = __builtin_amdgcn_mfma_f32_16x16x32_bf16(af[i], bfr[j], acc[i][j], 0, 0, 0);
  }

  const float* bias = d.bias + (size_t)r * d.biasStride;
  float bcol[8];
  #pragma unroll
  for (int j = 0; j < 8; ++j) bcol[j] = bias[j * 16 + m16];

  #pragma unroll
  for (int i = 0; i < 2; ++i) {
    #pragma unroll
    for (int p = 0; p < 4; ++p) {
      int grow = rowBase + wave * 32 + i * 16 + quad * 4 + p;
      if (grow >= d.M) continue;
      if (d.cKind == 0) {
        float* Crow = (float*)d.C + (size_t)r * d.cStride + (size_t)grow * d.ldc;
        #pragma unroll
        for (int j = 0; j < 8; ++j) {
          float v = acc[i][j][p] + bcol[j];
          if (d.relu) v = fmaxf(v, 0.f);
          Crow[j * 16 + m16] = v;
        }
      } else {
        ushort* Crow = (ushort*)d.C + (size_t)r * d.cStride + (size_t)grow * d.ldc;
        #pragma unroll
        for (int j = 0; j < 8; ++j) {
          float v = acc[i][j][p] + bcol[j];
          if (d.relu) v = fmaxf(v, 0.f);
          Crow[j * 16 + m16] = f2bf(v);
        }
      }
    }
  }
}

// feat0 columns 128..255 <- bf16(tss[nid] | rs[nid])
__global__ void gather0_kernel(const float* __restrict__ tss, const float* __restrict__ rs,
                               const int* __restrict__ nid, int N, ushort* __restrict__ feat)
{
  int gid = blockIdx.x * blockDim.x + threadIdx.x;
  if (gid >= N * 32) return;
  int n = gid >> 5, q = gid & 31;
  int id = nid[n];
  float4 v = (q < 16) ? *(const float4*)(tss + (size_t)id * 64 + q * 4)
                      : *(const float4*)(rs  + (size_t)id * 64 + (q - 16) * 4);
  uint2 pk; pk.x = pack2(v.x, v.y); pk.y = pack2(v.z, v.w);
  *(uint2*)(feat + (size_t)n * 256 + 128 + q * 4) = pk;
}

// ---------------- CSR build (batched over R=3 relations) ----------------
__global__ void zero_int(int* __restrict__ p, int n)
{
  int i = blockIdx.x * blockDim.x + threadIdx.x;
  if (i < n) p[i] = 0;
}

__global__ void count_deg(const int* __restrict__ edst, int E, int N, int* __restrict__ deg)
{
  int e = blockIdx.x * blockDim.x + threadIdx.x;
  int r = blockIdx.y;
  if (e < E) atomicAdd(&deg[r * N + edst[(size_t)r * E + e]], 1);
}

__global__ __launch_bounds__(1024) void scan_kernel(
    const int* __restrict__ deg, int* __restrict__ rowptr,
    int* __restrict__ cursor, int N)
{
  __shared__ int wtot[16];
  __shared__ int chunk_total_s;
  const int tid = threadIdx.x, lane = tid & 63, wid = tid >> 6;
  int running = 0;
  for (int base = 0; base < N; base += 1024) {
    int i = base + tid;
    int v = (i < N) ? deg[i] : 0;
    int incl = v;
    #pragma unroll
    for (int o = 1; o < 64; o <<= 1) {
      int t = __shfl_up(incl, o);
      if (lane >= o) incl += t;
    }
    if (lane == 63) wtot[wid] = incl;
    __syncthreads();
    if (wid == 0 && lane < 16) {
      int t = wtot[lane];
      int inc = t;
      #pragma unroll
      for (int o = 1; o < 16; o <<= 1) {
        int u = __shfl_up(inc, o);
        if (lane >= o) inc += u;
      }
      wtot[lane] = inc - t;
      if (lane == 15) chunk_total_s = inc;
    }
    __syncthreads();
    int excl = running + wtot[wid] + (incl - v);
    if (i < N) { rowptr[i] = excl; cursor[i] = 0; }
    running += chunk_total_s;
    __syncthreads();
  }
  if (tid == 0) rowptr[N] = running;
}

__global__ void fill_csr(const int* __restrict__ esrc, const int* __restrict__ edst,
                         int E, int N, const int* __restrict__ rowptr,
                         int* __restrict__ cursor, int* __restrict__ csr)
{
  int e = blockIdx.x * blockDim.x + threadIdx.x;
  int r = blockIdx.y;
  if (e >= E) return;
  int d = r * N + edst[(size_t)r * E + e];
  int pos = atomicAdd(&cursor[d], 1);
  csr[rowptr[d] + pos] = esrc[(size_t)r * E + e];
}

// one wave per (relation, chunk-local dst node): bf16 gather + sum/max
__global__ __launch_bounds__(256) void agg_kernel(
    const ushort* __restrict__ feat, const int* __restrict__ csr,
    const int* __restrict__ rowptr, int N, int c0, int cr, int CH,
    ushort* __restrict__ aggS, ushort* __restrict__ aggM, float* __restrict__ invdeg)
{
  const int wid = threadIdx.x >> 6, lane = threadIdx.x & 63;
  const int node = blockIdx.x * 4 + wid;
  if (node >= cr) return;
  const int g = blockIdx.y * N + c0 + node;
  const int o = blockIdx.y * CH + node;
  const int start = rowptr[g], end = rowptr[g + 1];
  const int j = lane * 4;                       // ushort offset
  float s0 = 0.f, s1 = 0.f, s2 = 0.f, s3 = 0.f;
  float m0 = -INFINITY, m1 = -INFINITY, m2 = -INFINITY, m3 = -INFINITY;
  for (int e = start; e < end; ++e) {
    int src = csr[e];
    uint2 v = *(const uint2*)(feat + (size_t)src * 256 + j);
    float a0 = bf2f(v.x & 0xFFFFu), a1 = bf2f(v.x >> 16);
    float a2 = bf2f(v.y & 0xFFFFu), a3 = bf2f(v.y >> 16);
    s0 += a0; s1 += a1; s2 += a2; s3 += a3;
    m0 = fmaxf(m0, a0); m1 = fmaxf(m1, a1);
    m2 = fmaxf(m2, a2); m3 = fmaxf(m3, a3);
  }
  if (end == start) { m0 = m1 = m2 = m3 = 0.f; }
  uint2 ps; ps.x = pack2(s0, s1); ps.y = pack2(s2, s3);
  *(uint2*)(aggS + (size_t)o * 256 + j) = ps;
  uint2 pm; pm.x = pack2(m0, m1); pm.y = pack2(m2, m3);
  *(uint2*)(aggM + (size_t)o * 256 + j) = pm;
  if (lane == 0) invdeg[o] = 1.f / fmaxf((float)(end - start), 1.f);
}

// ---------------- attention / combine ----------------
__global__ __launch_bounds__(256) void attn_stat(
    const float* __restrict__ z, const float* __restrict__ w1,
    const float* __restrict__ b1, const float* __restrict__ w2,
    int N, float* __restrict__ wsum)
{
  int r = blockIdx.y;
  int nb = blockIdx.x * 32;
  const float* zr = z + (size_t)r * N * 128;
  __shared__ float zl[32][128];
  #pragma unroll
  for (int i = 0; i < 4; ++i) {
    int q = threadIdx.x + 256 * i;
    int row = q >> 5, c4 = (q & 31) * 4;
    float4 v = make_float4(0.f, 0.f, 0.f, 0.f);
    if (nb + row < N) v = *(const float4*)(zr + (size_t)(nb + row) * 128 + c4);
    *(float4*)&zl[row][c4] = v;
  }
  __syncthreads();
  int col = threadIdx.x & 127, ng = threadIdx.x >> 7;
  float acc[16];
  #pragma unroll
  for (int n = 0; n < 16; ++n) acc[n] = 0.f;
  for (int k = 0; k < 128; ++k) {
    float wv = w1[k * 128 + col];
    #pragma unroll
    for (int n = 0; n < 16; ++n) acc[n] = fmaf(zl[ng*16 + n][k], wv, acc[n]);
  }
  float w2v = w2[col], b1v = b1[col];
  float local = 0.f;
  #pragma unroll
  for (int n = 0; n < 16; ++n)
    if (nb + ng*16 + n < N) local += tanhf(acc[n] + b1v) * w2v;
  #pragma unroll
  for (int o = 32; o > 0; o >>= 1) local += __shfl_down(local, o);
  __shared__ float red[4];
  if ((threadIdx.x & 63) == 0) red[threadIdx.x >> 6] = local;
  __syncthreads();
  if (threadIdx.x == 0) atomicAdd(&wsum[r], red[0] + red[1] + red[2] + red[3]);
}

__global__ void zero3(float* p) { if (threadIdx.x < 3) p[threadIdx.x] = 0.f; }

__global__ void beta_kernel(const float* __restrict__ wsum, float invN, float* __restrict__ beta) {
  float w0 = wsum[0] * invN, w1 = wsum[1] * invN, w2 = wsum[2] * invN;
  float m  = fmaxf(w0, fmaxf(w1, w2));
  float e0 = expf(w0 - m), e1 = expf(w1 - m), e2 = expf(w2 - m);
  float s  = e0 + e1 + e2;
  beta[0] = e0 / s; beta[1] = e1 / s; beta[2] = e2 / s;
}

// feat1 = bf16[relu(sum_r beta[r]*z1[r]) | tss[nid] | rs[nid]]
__global__ __launch_bounds__(256) void combine1_kernel(
    const float* __restrict__ z1, const float* __restrict__ beta,
    const float* __restrict__ tss, const float* __restrict__ rs,
    const int* __restrict__ nid, int N, ushort* __restrict__ feat1)
{
  int n = blockIdx.x, t = threadIdx.x;
  size_t NH = (size_t)N * 128;
  if (t < 128) {
    float v = beta[0] * z1[(size_t)n*128 + t] + beta[1] * z1[NH + (size_t)n*128 + t]
            + beta[2] * z1[2*NH + (size_t)n*128 + t];
    feat1[(size_t)n*256 + t] = f2bf(fmaxf(v, 0.f));
  } else {
    int j = t - 128;
    int id = nid[n];
    float v = (j < 64) ? tss[(size_t)id*64 + j] : rs[(size_t)id*64 + j - 64];
    feat1[(size_t)n*256 + t] = f2bf(v);
  }
}

__global__ __launch_bounds__(128) void combine2_pred(
    const float* __restrict__ z2, const float* __restrict__ beta, int N,
    const float* __restrict__ pw, const float* __restrict__ pb, float* __restrict__ out)
{
  int n = blockIdx.x, t = threadIdx.x;
  size_t NH = (size_t)N * 128;
  float h = beta[0] * z2[(size_t)n*128 + t] + beta[1] * z2[NH + (size_t)n*128 + t]
          + beta[2] * z2[2*NH + (size_t)n*128 + t];
  float p = h * pw[t];
  #pragma unroll
  for (int o = 32; o > 0; o >>= 1) p += __shfl_down(p, o);
  __shared__ float red[2];
  if ((t & 63) == 0) red[t >> 6] = p;
  __syncthreads();
  if (t == 0) {
    float v = red[0] + red[1] + pb[0];
    out[n] = 1.f / (1.f + expf(-v));
  }
}

extern "C" void kernel_launch(void* const* d_in, const int* in_sizes, int n_in,
                              void* d_out, int out_size, void* d_ws, size_t ws_size,
                              hipStream_t stream)
{
  const float* x_user  = (const float*)d_in[0];
  const float* tss     = (const float*)d_in[1];
  const float* rs      = (const float*)d_in[2];
  const int* src_nid0  = (const int*)d_in[3];
  const int* src_nid1  = (const int*)d_in[4];
  const int* e0_src    = (const int*)d_in[5];
  const int* e0_dst    = (const int*)d_in[6];
  const int* e1_src    = (const int*)d_in[7];
  const int* e1_dst    = (const int*)d_in[8];
  const float* embed_w = (const float*)d_in[9];
  const float* embed_b = (const float*)d_in[10];
  const float* l1w[3]  = {(const float*)d_in[11], (const float*)d_in[13], (const float*)d_in[15]};
  const float* l1b[3]  = {(const float*)d_in[12], (const float*)d_in[14], (const float*)d_in[16]};
  const float* l2w[3]  = {(const float*)d_in[17], (const float*)d_in[19], (const float*)d_in[21]};
  const float* l2b[3]  = {(const float*)d_in[18], (const float*)d_in[20], (const float*)d_in[22]};
  const float* attn_w1 = (const float*)d_in[23];
  const float* attn_b1 = (const float*)d_in[24];
  const float* attn_w2 = (const float*)d_in[25];
  const float* pred_w  = (const float*)d_in[26];
  const float* pred_b  = (const float*)d_in[27];
  float* out = (float*)d_out;

  const int N0 = in_sizes[0] / 128;
  const int N1 = in_sizes[4];
  const int N2 = out_size;
  const int E0 = in_sizes[5] / 3;
  const int E1 = in_sizes[7] / 3;

  char* wp = (char*)d_ws;
  auto walloc = [&](size_t bytes) {
    char* p = wp; wp += (bytes + 255) & ~(size_t)255; return p;
  };
  // Fixed allocations (~117 MB)
  ushort* feat0  = (ushort*)walloc((size_t)N0 * 256 * 2);      // bf16
  ushort* inp    = (ushort*)walloc((size_t)3 * N1 * 256 * 2);  // bf16
  float*  z      = (float*)walloc((size_t)3 * N1 * 128 * 4);   // fp32
  ushort* wt_emb = (ushort*)walloc((size_t)128 * 128 * 2);
  ushort* wt_fc1[2], *wt_fc2[2], *wt_fc3[2];
  for (int l = 0; l < 2; ++l) {
    wt_fc1[l] = (ushort*)walloc((size_t)3 * 256 * 128 * 2);
    wt_fc2[l] = (ushort*)walloc((size_t)3 * 768 * 128 * 2);
    wt_fc3[l] = (ushort*)walloc((size_t)3 * 256 * 128 * 2);
  }
  int*   degcnt = (int*)walloc((size_t)3 * N1 * 4);
  int*   rowptr = (int*)walloc((size_t)(3 * N1 + 1) * 4);
  int*   csr    = (int*)walloc((size_t)3 * E0 * 4);
  float* small  = (float*)walloc(256);
  float* wsum = small;
  float* beta = small + 4;
  ushort* feat1 = feat0;

  // Adaptive agg chunk size (bf16 agg buffers)
  size_t used = (size_t)(wp - (char*)d_ws);
  size_t avail = (ws_size > used + 65536) ? (ws_size - used - 65536) : 0;
  const size_t per_row = (size_t)3 * (2 * 256 * 2 + 4 + 64);
  int CH = (int)(avail / per_row);
  if (CH > N1) CH = N1;
  if (CH < 1024) CH = 1024;
  ushort* aggS   = (ushort*)walloc((size_t)3 * CH * 256 * 2);
  ushort* aggM   = (ushort*)walloc((size_t)3 * CH * 256 * 2);
  float*  invdeg = (float*)walloc((size_t)3 * CH * 4);
  (void)n_in;

  // ---- weight prep: transpose + bf16 convert ----
  prep_w<<<dim3(1, 128, 1), 256, 0, stream>>>(embed_w, wt_emb, 128);
  for (int l = 0; l < 2; ++l) {
    const float* const* lw = l ? l2w : l1w;
    prep_w<<<dim3(1, 128, 3), 256, 0, stream>>>(lw[0], wt_fc1[l], 256);
    prep_w<<<dim3(3, 128, 3), 256, 0, stream>>>(lw[1], wt_fc2[l], 768);
    prep_w<<<dim3(1, 128, 3), 256, 0, stream>>>(lw[2], wt_fc3[l], 256);
  }

  GemmDesc dz = {};

  // ---- feat0 = bf16[x@embed | tss | rs] ----
  {
    GemmDesc d = {x_user, 128, 0, 0, wt_emb, 0, embed_b, 0,
                  feat0, 256, 0, 1, N0, 128, 0,
                  aggM, aggS, invdeg, 0, 0};
    gemm_mfma<<<dim3((N0 + 127) / 128, 1, 1), 256, 0, stream>>>(d, dz);
  }
  gather0_kernel<<<(N0 * 32 + 255) / 256, 256, 0, stream>>>(tss, rs, src_nid0, N0, feat0);

  // ---- two conv layers ----
  for (int layer = 0; layer < 2; ++layer) {
    const ushort* featS = layer ? feat1 : feat0;
    int Nd = layer ? N2 : N1;
    int E  = layer ? E1 : E0;
    const int* es = layer ? e1_src : e0_src;
    const int* ed = layer ? e1_dst : e0_dst;
    const float* const* lb = layer ? l2b : l1b;

    // CSR build for all 3 relations
    zero_int<<<(3 * Nd + 255) / 256, 256, 0, stream>>>(degcnt, 3 * Nd);
    count_deg<<<dim3((E + 255) / 256, 3), 256, 0, stream>>>(ed, E, Nd, degcnt);
    scan_kernel<<<1, 1024, 0, stream>>>(degcnt, rowptr, degcnt, 3 * Nd);
    fill_csr<<<dim3((E + 255) / 256, 3), 256, 0, stream>>>(es, ed, E, Nd, rowptr, degcnt, csr);

    // chunked: agg -> fused fc2 (z=0, K=768 virtual) + fc1 (z=1, K=256)
    for (int c0 = 0; c0 < Nd; c0 += CH) {
      int cr = (Nd - c0 < CH) ? (Nd - c0) : CH;
      agg_kernel<<<dim3((cr + 3) / 4, 3), 256, 0, stream>>>(
          featS, csr, rowptr, Nd, c0, cr, CH, aggS, aggM, invdeg);
      GemmDesc d2 = {nullptr, 0, 0, 2, wt_fc2[layer], (size_t)768 * 128, lb[1], 128,
                     inp + (size_t)c0 * 256, 256, (size_t)Nd * 256, 1,
                     cr, 768, 1, aggS /*unused slot filled below*/, aggS, invdeg,
                     (size_t)CH * 256, CH};
      d2.aggM = aggM;
      GemmDesc d1 = {featS + (size_t)c0 * 256, 256, 0, 1, wt_fc1[layer], (size_t)256 * 128, lb[0], 128,
                     inp + 128 + (size_t)c0 * 256, 256, (size_t)Nd * 256, 1,
                     cr, 256, 1, aggM, aggS, invdeg, 0, 0};
      gemm_mfma<<<dim3((cr + 127) / 128, 3, 2), 256, 0, stream>>>(d2, d1);
    }
    // fc3 -> z (fp32)
    {
      GemmDesc d3 = {inp, 256, (size_t)Nd * 256, 1, wt_fc3[layer], (size_t)256 * 128, lb[2], 128,
                     z, 128, (size_t)Nd * 128, 0, Nd, 256, 0,
                     aggM, aggS, invdeg, 0, 0};
      gemm_mfma<<<dim3((Nd + 127) / 128, 3, 1), 256, 0, stream>>>(d3, dz);
    }

    zero3<<<1, 64, 0, stream>>>(wsum);
    attn_stat<<<dim3((Nd + 31) / 32, 3), 256, 0, stream>>>(z, attn_w1, attn_b1, attn_w2, Nd, wsum);
    beta_kernel<<<1, 1, 0, stream>>>(wsum, 1.0f / (float)Nd, beta);

    if (layer == 0) {
      combine1_kernel<<<N1, 256, 0, stream>>>(z, beta, tss, rs, src_nid1, N1, feat1);
    } else {
      combine2_pred<<<N2, 128, 0, stream>>>(z, beta, N2, pred_w, pred_b, out);
    }
  }
}

// Round 6
// 570.686 us; speedup vs baseline: 12.7342x; 1.1812x over previous
//
#include <hip/hip_runtime.h>
#include <math.h>

// ---------------------------------------------------------------------------
// IG_RGCN forward on MI355X. Round 6: launch-trim + MFMA attention + agg ILP.
//  - attn_mfma: z@w1 via 16x16x32 bf16 MFMA, tanh*w2 block-reduce, 1 atomic.
//    (replaces LDS-read-per-FMA attn_stat)
//  - agg_kernel: edge loop unrolled x4 (4 independent 512B gathers in flight)
//  - prep_all: all 8 weight transposes (incl attn w1) in one launch
//  - gather0 fused into embed GEMM epilogue; zero kernels -> hipMemsetAsync
//  - scan processes 4096 elems/iter (int4)
// ---------------------------------------------------------------------------

typedef short s16x8 __attribute__((ext_vector_type(8)));
typedef float f32x4 __attribute__((ext_vector_type(4)));

__device__ __forceinline__ ushort f2bf(float f) {
  unsigned u = __float_as_uint(f);
  return (ushort)((u + 0x7FFFu + ((u >> 16) & 1u)) >> 16);
}
__device__ __forceinline__ float bf2f(unsigned hbits) {
  return __uint_as_float(hbits << 16);
}
__device__ __forceinline__ unsigned pack2(float lo, float hi) {
  return (unsigned)f2bf(lo) | ((unsigned)f2bf(hi) << 16);
}

// ---- one-shot weight prep: 8 tensors, W[r][K][128] fp32 -> Wt[r][128][K] bf16
struct PrepAll {
  const float* src[8];
  ushort* dst[8];
  int K[8];
  int total[8];   // R*K*128
};

__global__ __launch_bounds__(256) void prep_all(PrepAll P)
{
  int t = blockIdx.z;
  int off = blockIdx.x * 256 + threadIdx.x;
  if (off >= P.total[t]) return;
  int K = P.K[t];
  int k = off % K;
  int n = (off / K) & 127;
  int r = off / (K * 128);
  P.dst[t][off] = f2bf(P.src[t][((size_t)r * K + k) * 128 + n]);
}

struct GemmDesc {
  const void* A; int lda; size_t aStride; int aKind;   // 0 fp32, 1 bf16, 2 virtual agg
  const ushort* Wt; size_t wStride;                    // [128][K] bf16 per relation
  const float* bias; int biasStride;
  void* C; int ldc; size_t cStride; int cKind;         // 0 fp32, 1 bf16
  int M, K, relu;
  const ushort* aggM; const ushort* aggS; const float* invdeg;
  size_t aggStride; int invStride;
  // optional fused gather (embed only): fill C cols 128..255 with bf16(tss|rs)[nid]
  const int* gnid; const float* gtss; const float* grs;
};

// C[M,128] = act(A[M,K] @ W + b); blockIdx.y = relation, .z = descriptor
__global__ __launch_bounds__(256) void gemm_mfma(GemmDesc d0, GemmDesc d1)
{
  const GemmDesc d = blockIdx.z ? d1 : d0;
  const int r = blockIdx.y;
  __shared__ ushort As[128 * 32];   // row-major, row stride 32
  __shared__ ushort Bs[128 * 32];   // col-major: Bs[col*32 + k]

  const int tid = threadIdx.x;
  const int wave = tid >> 6, lane = tid & 63;
  const int m16 = lane & 15, quad = lane >> 4;
  const int rowBase = blockIdx.x * 128;
  const ushort* Wt = d.Wt + (size_t)r * d.wStride;

  f32x4 acc[2][8];
  #pragma unroll
  for (int i = 0; i < 2; ++i)
    #pragma unroll
    for (int j = 0; j < 8; ++j)
      #pragma unroll
      for (int p = 0; p < 4; ++p) acc[i][j][p] = 0.f;

  for (int k0 = 0; k0 < d.K; k0 += 32) {
    __syncthreads();
    if (d.aKind == 1) {                       // bf16 rows
      const ushort* Ab = (const ushort*)d.A + (size_t)r * d.aStride;
      #pragma unroll
      for (int i = 0; i < 2; ++i) {
        int q = tid + 256 * i;
        int row = q >> 2, c = (q & 3) * 8;
        int grow = rowBase + row;
        uint4 v = make_uint4(0, 0, 0, 0);
        if (grow < d.M) v = *(const uint4*)(Ab + (size_t)grow * d.lda + k0 + c);
        *(uint4*)&As[row * 32 + c] = v;
      }
    } else if (d.aKind == 0) {                // fp32 rows, convert
      const float* Ab = (const float*)d.A + (size_t)r * d.aStride;
      #pragma unroll
      for (int i = 0; i < 4; ++i) {
        int q = tid + 256 * i;
        int row = q >> 3, c = (q & 7) * 4;
        int grow = rowBase + row;
        float4 f = make_float4(0.f, 0.f, 0.f, 0.f);
        if (grow < d.M) f = *(const float4*)(Ab + (size_t)grow * d.lda + k0 + c);
        uint2 pk; pk.x = pack2(f.x, f.y); pk.y = pack2(f.z, f.w);
        *(uint2*)&As[row * 32 + c] = pk;
      }
    } else {                                  // virtual [mx | sum*invdeg | sum]
      int seg = k0 >> 8, jj = k0 & 255;
      const ushort* Ab = (seg == 0 ? d.aggM : d.aggS) + (size_t)r * d.aggStride;
      const float* idg = d.invdeg + (size_t)r * d.invStride;
      #pragma unroll
      for (int i = 0; i < 2; ++i) {
        int q = tid + 256 * i;
        int row = q >> 2, c = (q & 3) * 8;
        int grow = rowBase + row;
        uint4 v = make_uint4(0, 0, 0, 0);
        if (grow < d.M) {
          v = *(const uint4*)(Ab + (size_t)grow * 256 + jj + c);
          if (seg == 1) {
            float s = idg[grow];
            v.x = pack2(bf2f(v.x & 0xFFFFu) * s, bf2f(v.x >> 16) * s);
            v.y = pack2(bf2f(v.y & 0xFFFFu) * s, bf2f(v.y >> 16) * s);
            v.z = pack2(bf2f(v.z & 0xFFFFu) * s, bf2f(v.z >> 16) * s);
            v.w = pack2(bf2f(v.w & 0xFFFFu) * s, bf2f(v.w >> 16) * s);
          }
        }
        *(uint4*)&As[row * 32 + c] = v;
      }
    }
    #pragma unroll
    for (int i = 0; i < 2; ++i) {             // B tile: 128 cols x 32 k
      int q = tid + 256 * i;
      int col = q >> 2, c = (q & 3) * 8;
      uint4 v = *(const uint4*)(Wt + (size_t)col * d.K + k0 + c);
      *(uint4*)&Bs[col * 32 + c] = v;
    }
    __syncthreads();

    s16x8 af[2], bfr[8];
    af[0] = *(const s16x8*)&As[(wave * 32 + m16) * 32 + quad * 8];
    af[1] = *(const s16x8*)&As[(wave * 32 + 16 + m16) * 32 + quad * 8];
    #pragma unroll
    for (int j = 0; j < 8; ++j)
      bfr[j] = *(const s16x8*)&Bs[(j * 16 + m16) * 32 + quad * 8];
    #pragma unroll
    for (int i = 0; i < 2; ++i)
      #pragma unroll
      for (int j = 0; j < 8; ++j)
        acc[i][j] = __builtin_amdgcn_mfma_f32_16x16x32_bf16(af[i], bfr[j], acc[i][j], 0, 0, 0);
  }

  const float* bias = d.bias + (size_t)r * d.biasStride;
  float bcol[8];
  #pragma unroll
  for (int j = 0; j < 8; ++j) bcol[j] = bias[j * 16 + m16];

  #pragma unroll
  for (int i = 0; i < 2; ++i) {
    #pragma unroll
    for (int p = 0; p < 4; ++p) {
      int grow = rowBase + wave * 32 + i * 16 + quad * 4 + p;
      if (grow >= d.M) continue;
      if (d.cKind == 0) {
        float* Crow = (float*)d.C + (size_t)r * d.cStride + (size_t)grow * d.ldc;
        #pragma unroll
        for (int j = 0; j < 8; ++j) {
          float v = acc[i][j][p] + bcol[j];
          if (d.relu) v = fmaxf(v, 0.f);
          Crow[j * 16 + m16] = v;
        }
      } else {
        ushort* Crow = (ushort*)d.C + (size_t)r * d.cStride + (size_t)grow * d.ldc;
        #pragma unroll
        for (int j = 0; j < 8; ++j) {
          float v = acc[i][j][p] + bcol[j];
          if (d.relu) v = fmaxf(v, 0.f);
          Crow[j * 16 + m16] = f2bf(v);
        }
      }
    }
  }

  // fused gather (embed): C cols 128..255 <- bf16(tss[nid] | rs[nid])
  if (d.gnid) {
    #pragma unroll
    for (int i = 0; i < 16; ++i) {
      int q = tid + 256 * i;              // 4096 tasks: 128 rows x 32 chunks
      int row = q >> 5, c = q & 31;
      int grow = rowBase + row;
      if (grow >= d.M) continue;
      int id = d.gnid[grow];
      float4 v = (c < 16) ? *(const float4*)(d.gtss + (size_t)id * 64 + c * 4)
                          : *(const float4*)(d.grs  + (size_t)id * 64 + (c - 16) * 4);
      uint2 pk; pk.x = pack2(v.x, v.y); pk.y = pack2(v.z, v.w);
      *(uint2*)((ushort*)d.C + (size_t)grow * d.ldc + 128 + c * 4) = pk;
    }
  }
}

// ---- MFMA semantic attention: wsum[r] += sum_n tanh(z[r,n,:]@w1+b1)@w2
__global__ __launch_bounds__(256) void attn_mfma(
    const float* __restrict__ z, const ushort* __restrict__ w1t,
    const float* __restrict__ b1, const float* __restrict__ w2,
    int N, float* __restrict__ wsum)
{
  const int r = blockIdx.y;
  const float* zr = z + (size_t)r * N * 128;
  __shared__ ushort As[128 * 32];
  __shared__ ushort Bs[128 * 32];

  const int tid = threadIdx.x;
  const int wave = tid >> 6, lane = tid & 63;
  const int m16 = lane & 15, quad = lane >> 4;
  const int rowBase = blockIdx.x * 128;

  f32x4 acc[2][8];
  #pragma unroll
  for (int i = 0; i < 2; ++i)
    #pragma unroll
    for (int j = 0; j < 8; ++j)
      #pragma unroll
      for (int p = 0; p < 4; ++p) acc[i][j][p] = 0.f;

  for (int k0 = 0; k0 < 128; k0 += 32) {
    __syncthreads();
    #pragma unroll
    for (int i = 0; i < 4; ++i) {
      int q = tid + 256 * i;
      int row = q >> 3, c = (q & 7) * 4;
      int grow = rowBase + row;
      float4 f = make_float4(0.f, 0.f, 0.f, 0.f);
      if (grow < N) f = *(const float4*)(zr + (size_t)grow * 128 + k0 + c);
      uint2 pk; pk.x = pack2(f.x, f.y); pk.y = pack2(f.z, f.w);
      *(uint2*)&As[row * 32 + c] = pk;
    }
    #pragma unroll
    for (int i = 0; i < 2; ++i) {
      int q = tid + 256 * i;
      int col = q >> 2, c = (q & 3) * 8;
      uint4 v = *(const uint4*)(w1t + (size_t)col * 128 + k0 + c);
      *(uint4*)&Bs[col * 32 + c] = v;
    }
    __syncthreads();

    s16x8 af[2], bfr[8];
    af[0] = *(const s16x8*)&As[(wave * 32 + m16) * 32 + quad * 8];
    af[1] = *(const s16x8*)&As[(wave * 32 + 16 + m16) * 32 + quad * 8];
    #pragma unroll
    for (int j = 0; j < 8; ++j)
      bfr[j] = *(const s16x8*)&Bs[(j * 16 + m16) * 32 + quad * 8];
    #pragma unroll
    for (int i = 0; i < 2; ++i)
      #pragma unroll
      for (int j = 0; j < 8; ++j)
        acc[i][j] = __builtin_amdgcn_mfma_f32_16x16x32_bf16(af[i], bfr[j], acc[i][j], 0, 0, 0);
  }

  float b1c[8], w2c[8];
  #pragma unroll
  for (int j = 0; j < 8; ++j) { b1c[j] = b1[j * 16 + m16]; w2c[j] = w2[j * 16 + m16]; }

  float local = 0.f;
  #pragma unroll
  for (int i = 0; i < 2; ++i)
    #pragma unroll
    for (int p = 0; p < 4; ++p) {
      int grow = rowBase + wave * 32 + i * 16 + quad * 4 + p;
      if (grow >= N) continue;
      #pragma unroll
      for (int j = 0; j < 8; ++j)
        local += tanhf(acc[i][j][p] + b1c[j]) * w2c[j];
    }
  #pragma unroll
  for (int o = 32; o > 0; o >>= 1) local += __shfl_down(local, o);
  __shared__ float red[4];
  if (lane == 0) red[wave] = local;
  __syncthreads();
  if (tid == 0) atomicAdd(&wsum[r], red[0] + red[1] + red[2] + red[3]);
}

// ---------------- CSR build (batched over R=3 relations) ----------------
__global__ void count_deg(const int* __restrict__ edst, int E, int N, int* __restrict__ deg)
{
  int e = blockIdx.x * blockDim.x + threadIdx.x;
  int r = blockIdx.y;
  if (e < E) atomicAdd(&deg[r * N + edst[(size_t)r * E + e]], 1);
}

// single-block exclusive scan, 4096 elems/iter; zeroes cursor (aliases deg)
__global__ __launch_bounds__(1024) void scan_kernel(
    const int* __restrict__ deg, int* __restrict__ rowptr,
    int* __restrict__ cursor, int N)
{
  __shared__ int wtot[16];
  __shared__ int chunk_total_s;
  const int tid = threadIdx.x, lane = tid & 63, wid = tid >> 6;
  int running = 0;
  for (int base = 0; base < N; base += 4096) {
    int i0 = base + tid * 4;
    int d0 = 0, d1 = 0, d2 = 0, d3 = 0;
    if (i0 < N) {
      if (i0 + 3 < N) { int4 t = *(const int4*)(deg + i0); d0 = t.x; d1 = t.y; d2 = t.z; d3 = t.w; }
      else { d0 = deg[i0]; if (i0+1 < N) d1 = deg[i0+1]; if (i0+2 < N) d2 = deg[i0+2]; }
    }
    int tsum = d0 + d1 + d2 + d3;
    int incl = tsum;
    #pragma unroll
    for (int o = 1; o < 64; o <<= 1) {
      int t = __shfl_up(incl, o);
      if (lane >= o) incl += t;
    }
    if (lane == 63) wtot[wid] = incl;
    __syncthreads();
    if (wid == 0 && lane < 16) {
      int t = wtot[lane];
      int inc = t;
      #pragma unroll
      for (int o = 1; o < 16; o <<= 1) {
        int u = __shfl_up(inc, o);
        if (lane >= o) inc += u;
      }
      wtot[lane] = inc - t;
      if (lane == 15) chunk_total_s = inc;
    }
    __syncthreads();
    int excl = running + wtot[wid] + (incl - tsum);
    if (i0 < N) {
      int e1 = excl + d0, e2 = e1 + d1, e3 = e2 + d2;
      if (i0 + 3 < N) {
        *(int4*)(rowptr + i0) = make_int4(excl, e1, e2, e3);
        *(int4*)(cursor + i0) = make_int4(0, 0, 0, 0);
      } else {
        rowptr[i0] = excl; cursor[i0] = 0;
        if (i0+1 < N) { rowptr[i0+1] = e1; cursor[i0+1] = 0; }
        if (i0+2 < N) { rowptr[i0+2] = e2; cursor[i0+2] = 0; }
      }
    }
    running += chunk_total_s;
    __syncthreads();
  }
  if (tid == 0) rowptr[N] = running;
}

__global__ void fill_csr(const int* __restrict__ esrc, const int* __restrict__ edst,
                         int E, int N, const int* __restrict__ rowptr,
                         int* __restrict__ cursor, int* __restrict__ csr)
{
  int e = blockIdx.x * blockDim.x + threadIdx.x;
  int r = blockIdx.y;
  if (e >= E) return;
  int d = r * N + edst[(size_t)r * E + e];
  int pos = atomicAdd(&cursor[d], 1);
  csr[rowptr[d] + pos] = esrc[(size_t)r * E + e];
}

// one wave per (relation, chunk-local dst node): bf16 gather, x4-unrolled ILP
__global__ __launch_bounds__(256) void agg_kernel(
    const ushort* __restrict__ feat, const int* __restrict__ csr,
    const int* __restrict__ rowptr, int N, int c0, int cr, int CH,
    ushort* __restrict__ aggS, ushort* __restrict__ aggM, float* __restrict__ invdeg)
{
  const int wid = threadIdx.x >> 6, lane = threadIdx.x & 63;
  const int node = blockIdx.x * 4 + wid;
  if (node >= cr) return;
  const int g = blockIdx.y * N + c0 + node;
  const int o = blockIdx.y * CH + node;
  const int start = rowptr[g], end = rowptr[g + 1];
  const int j = lane * 4;
  float s0 = 0.f, s1 = 0.f, s2 = 0.f, s3 = 0.f;
  float m0 = -INFINITY, m1 = -INFINITY, m2 = -INFINITY, m3 = -INFINITY;
  int e = start;
  for (; e + 4 <= end; e += 4) {
    int sa = csr[e], sb = csr[e+1], sc = csr[e+2], sd = csr[e+3];
    uint2 va = *(const uint2*)(feat + (size_t)sa * 256 + j);
    uint2 vb = *(const uint2*)(feat + (size_t)sb * 256 + j);
    uint2 vc = *(const uint2*)(feat + (size_t)sc * 256 + j);
    uint2 vd = *(const uint2*)(feat + (size_t)sd * 256 + j);
    float a0, a1, a2, a3;
    a0 = bf2f(va.x & 0xFFFFu); a1 = bf2f(va.x >> 16); a2 = bf2f(va.y & 0xFFFFu); a3 = bf2f(va.y >> 16);
    s0 += a0; s1 += a1; s2 += a2; s3 += a3;
    m0 = fmaxf(m0, a0); m1 = fmaxf(m1, a1); m2 = fmaxf(m2, a2); m3 = fmaxf(m3, a3);
    a0 = bf2f(vb.x & 0xFFFFu); a1 = bf2f(vb.x >> 16); a2 = bf2f(vb.y & 0xFFFFu); a3 = bf2f(vb.y >> 16);
    s0 += a0; s1 += a1; s2 += a2; s3 += a3;
    m0 = fmaxf(m0, a0); m1 = fmaxf(m1, a1); m2 = fmaxf(m2, a2); m3 = fmaxf(m3, a3);
    a0 = bf2f(vc.x & 0xFFFFu); a1 = bf2f(vc.x >> 16); a2 = bf2f(vc.y & 0xFFFFu); a3 = bf2f(vc.y >> 16);
    s0 += a0; s1 += a1; s2 += a2; s3 += a3;
    m0 = fmaxf(m0, a0); m1 = fmaxf(m1, a1); m2 = fmaxf(m2, a2); m3 = fmaxf(m3, a3);
    a0 = bf2f(vd.x & 0xFFFFu); a1 = bf2f(vd.x >> 16); a2 = bf2f(vd.y & 0xFFFFu); a3 = bf2f(vd.y >> 16);
    s0 += a0; s1 += a1; s2 += a2; s3 += a3;
    m0 = fmaxf(m0, a0); m1 = fmaxf(m1, a1); m2 = fmaxf(m2, a2); m3 = fmaxf(m3, a3);
  }
  for (; e < end; ++e) {
    int src = csr[e];
    uint2 v = *(const uint2*)(feat + (size_t)src * 256 + j);
    float a0 = bf2f(v.x & 0xFFFFu), a1 = bf2f(v.x >> 16);
    float a2 = bf2f(v.y & 0xFFFFu), a3 = bf2f(v.y >> 16);
    s0 += a0; s1 += a1; s2 += a2; s3 += a3;
    m0 = fmaxf(m0, a0); m1 = fmaxf(m1, a1); m2 = fmaxf(m2, a2); m3 = fmaxf(m3, a3);
  }
  if (end == start) { m0 = m1 = m2 = m3 = 0.f; }
  uint2 ps; ps.x = pack2(s0, s1); ps.y = pack2(s2, s3);
  *(uint2*)(aggS + (size_t)o * 256 + j) = ps;
  uint2 pm; pm.x = pack2(m0, m1); pm.y = pack2(m2, m3);
  *(uint2*)(aggM + (size_t)o * 256 + j) = pm;
  if (lane == 0) invdeg[o] = 1.f / fmaxf((float)(end - start), 1.f);
}

// ---------------- combine ----------------
__global__ void beta_kernel(const float* __restrict__ wsum, float invN, float* __restrict__ beta) {
  float w0 = wsum[0] * invN, w1 = wsum[1] * invN, w2 = wsum[2] * invN;
  float m  = fmaxf(w0, fmaxf(w1, w2));
  float e0 = expf(w0 - m), e1 = expf(w1 - m), e2 = expf(w2 - m);
  float s  = e0 + e1 + e2;
  beta[0] = e0 / s; beta[1] = e1 / s; beta[2] = e2 / s;
}

// feat1 = bf16[relu(sum_r beta[r]*z1[r]) | tss[nid] | rs[nid]]
__global__ __launch_bounds__(256) void combine1_kernel(
    const float* __restrict__ z1, const float* __restrict__ beta,
    const float* __restrict__ tss, const float* __restrict__ rs,
    const int* __restrict__ nid, int N, ushort* __restrict__ feat1)
{
  int n = blockIdx.x, t = threadIdx.x;
  size_t NH = (size_t)N * 128;
  if (t < 128) {
    float v = beta[0] * z1[(size_t)n*128 + t] + beta[1] * z1[NH + (size_t)n*128 + t]
            + beta[2] * z1[2*NH + (size_t)n*128 + t];
    feat1[(size_t)n*256 + t] = f2bf(fmaxf(v, 0.f));
  } else {
    int j = t - 128;
    int id = nid[n];
    float v = (j < 64) ? tss[(size_t)id*64 + j] : rs[(size_t)id*64 + j - 64];
    feat1[(size_t)n*256 + t] = f2bf(v);
  }
}

__global__ __launch_bounds__(128) void combine2_pred(
    const float* __restrict__ z2, const float* __restrict__ beta, int N,
    const float* __restrict__ pw, const float* __restrict__ pb, float* __restrict__ out)
{
  int n = blockIdx.x, t = threadIdx.x;
  size_t NH = (size_t)N * 128;
  float h = beta[0] * z2[(size_t)n*128 + t] + beta[1] * z2[NH + (size_t)n*128 + t]
          + beta[2] * z2[2*NH + (size_t)n*128 + t];
  float p = h * pw[t];
  #pragma unroll
  for (int o = 32; o > 0; o >>= 1) p += __shfl_down(p, o);
  __shared__ float red[2];
  if ((t & 63) == 0) red[t >> 6] = p;
  __syncthreads();
  if (t == 0) {
    float v = red[0] + red[1] + pb[0];
    out[n] = 1.f / (1.f + expf(-v));
  }
}

extern "C" void kernel_launch(void* const* d_in, const int* in_sizes, int n_in,
                              void* d_out, int out_size, void* d_ws, size_t ws_size,
                              hipStream_t stream)
{
  const float* x_user  = (const float*)d_in[0];
  const float* tss     = (const float*)d_in[1];
  const float* rs      = (const float*)d_in[2];
  const int* src_nid0  = (const int*)d_in[3];
  const int* src_nid1  = (const int*)d_in[4];
  const int* e0_src    = (const int*)d_in[5];
  const int* e0_dst    = (const int*)d_in[6];
  const int* e1_src    = (const int*)d_in[7];
  const int* e1_dst    = (const int*)d_in[8];
  const float* embed_w = (const float*)d_in[9];
  const float* embed_b = (const float*)d_in[10];
  const float* l1w[3]  = {(const float*)d_in[11], (const float*)d_in[13], (const float*)d_in[15]};
  const float* l1b[3]  = {(const float*)d_in[12], (const float*)d_in[14], (const float*)d_in[16]};
  const float* l2w[3]  = {(const float*)d_in[17], (const float*)d_in[19], (const float*)d_in[21]};
  const float* l2b[3]  = {(const float*)d_in[18], (const float*)d_in[20], (const float*)d_in[22]};
  const float* attn_w1 = (const float*)d_in[23];
  const float* attn_b1 = (const float*)d_in[24];
  const float* attn_w2 = (const float*)d_in[25];
  const float* pred_w  = (const float*)d_in[26];
  const float* pred_b  = (const float*)d_in[27];
  float* out = (float*)d_out;

  const int N0 = in_sizes[0] / 128;
  const int N1 = in_sizes[4];
  const int N2 = out_size;
  const int E0 = in_sizes[5] / 3;
  const int E1 = in_sizes[7] / 3;

  char* wp = (char*)d_ws;
  auto walloc = [&](size_t bytes) {
    char* p = wp; wp += (bytes + 255) & ~(size_t)255; return p;
  };
  // Fixed allocations (~117 MB)
  ushort* feat0  = (ushort*)walloc((size_t)N0 * 256 * 2);      // bf16
  ushort* inp    = (ushort*)walloc((size_t)3 * N1 * 256 * 2);  // bf16
  float*  z      = (float*)walloc((size_t)3 * N1 * 128 * 4);   // fp32
  ushort* wt_emb = (ushort*)walloc((size_t)128 * 128 * 2);
  ushort* wt_attn = (ushort*)walloc((size_t)128 * 128 * 2);
  ushort* wt_fc1[2], *wt_fc2[2], *wt_fc3[2];
  for (int l = 0; l < 2; ++l) {
    wt_fc1[l] = (ushort*)walloc((size_t)3 * 256 * 128 * 2);
    wt_fc2[l] = (ushort*)walloc((size_t)3 * 768 * 128 * 2);
    wt_fc3[l] = (ushort*)walloc((size_t)3 * 256 * 128 * 2);
  }
  int*   degcnt = (int*)walloc((size_t)3 * N1 * 4);
  int*   rowptr = (int*)walloc((size_t)(3 * N1 + 1) * 4);
  int*   csr    = (int*)walloc((size_t)3 * E0 * 4);
  float* small  = (float*)walloc(256);
  float* wsum = small;
  float* beta = small + 4;
  ushort* feat1 = feat0;

  // Adaptive agg chunk size (bf16 agg buffers)
  size_t used = (size_t)(wp - (char*)d_ws);
  size_t avail = (ws_size > used + 65536) ? (ws_size - used - 65536) : 0;
  const size_t per_row = (size_t)3 * (2 * 256 * 2 + 4 + 64);
  int CH = (int)(avail / per_row);
  if (CH > N1) CH = N1;
  if (CH < 1024) CH = 1024;
  ushort* aggS   = (ushort*)walloc((size_t)3 * CH * 256 * 2);
  ushort* aggM   = (ushort*)walloc((size_t)3 * CH * 256 * 2);
  float*  invdeg = (float*)walloc((size_t)3 * CH * 4);
  (void)n_in;

  // ---- weight prep: 8 tensors in one launch ----
  {
    PrepAll P;
    P.src[0] = embed_w;  P.dst[0] = wt_emb;    P.K[0] = 128; P.total[0] = 128 * 128;
    P.src[1] = attn_w1;  P.dst[1] = wt_attn;   P.K[1] = 128; P.total[1] = 128 * 128;
    P.src[2] = l1w[0];   P.dst[2] = wt_fc1[0]; P.K[2] = 256; P.total[2] = 3 * 256 * 128;
    P.src[3] = l1w[1];   P.dst[3] = wt_fc2[0]; P.K[3] = 768; P.total[3] = 3 * 768 * 128;
    P.src[4] = l1w[2];   P.dst[4] = wt_fc3[0]; P.K[4] = 256; P.total[4] = 3 * 256 * 128;
    P.src[5] = l2w[0];   P.dst[5] = wt_fc1[1]; P.K[5] = 256; P.total[5] = 3 * 256 * 128;
    P.src[6] = l2w[1];   P.dst[6] = wt_fc2[1]; P.K[6] = 768; P.total[6] = 3 * 768 * 128;
    P.src[7] = l2w[2];   P.dst[7] = wt_fc3[1]; P.K[7] = 256; P.total[7] = 3 * 256 * 128;
    prep_all<<<dim3((3 * 768 * 128 + 255) / 256, 1, 8), 256, 0, stream>>>(P);
  }

  GemmDesc dz = {};

  // ---- feat0 = bf16[x@embed | tss | rs] (gather fused into epilogue) ----
  {
    GemmDesc d{};
    d.A = x_user; d.lda = 128; d.aStride = 0; d.aKind = 0;
    d.Wt = wt_emb; d.wStride = 0; d.bias = embed_b; d.biasStride = 0;
    d.C = feat0; d.ldc = 256; d.cStride = 0; d.cKind = 1;
    d.M = N0; d.K = 128; d.relu = 0;
    d.aggM = aggM; d.aggS = aggS; d.invdeg = invdeg; d.aggStride = 0; d.invStride = 0;
    d.gnid = src_nid0; d.gtss = tss; d.grs = rs;
    gemm_mfma<<<dim3((N0 + 127) / 128, 1, 1), 256, 0, stream>>>(d, dz);
  }

  // ---- two conv layers ----
  for (int layer = 0; layer < 2; ++layer) {
    const ushort* featS = layer ? feat1 : feat0;
    int Nd = layer ? N2 : N1;
    int E  = layer ? E1 : E0;
    const int* es = layer ? e1_src : e0_src;
    const int* ed = layer ? e1_dst : e0_dst;
    const float* const* lb = layer ? l2b : l1b;

    // CSR build for all 3 relations
    hipMemsetAsync(degcnt, 0, (size_t)3 * Nd * 4, stream);
    count_deg<<<dim3((E + 255) / 256, 3), 256, 0, stream>>>(ed, E, Nd, degcnt);
    scan_kernel<<<1, 1024, 0, stream>>>(degcnt, rowptr, degcnt, 3 * Nd);
    fill_csr<<<dim3((E + 255) / 256, 3), 256, 0, stream>>>(es, ed, E, Nd, rowptr, degcnt, csr);

    // chunked: agg -> fused fc2 (z=0, K=768 virtual) + fc1 (z=1, K=256)
    for (int c0 = 0; c0 < Nd; c0 += CH) {
      int cr = (Nd - c0 < CH) ? (Nd - c0) : CH;
      agg_kernel<<<dim3((cr + 3) / 4, 3), 256, 0, stream>>>(
          featS, csr, rowptr, Nd, c0, cr, CH, aggS, aggM, invdeg);
      GemmDesc d2{};
      d2.A = nullptr; d2.lda = 0; d2.aStride = 0; d2.aKind = 2;
      d2.Wt = wt_fc2[layer]; d2.wStride = (size_t)768 * 128; d2.bias = lb[1]; d2.biasStride = 128;
      d2.C = inp + (size_t)c0 * 256; d2.ldc = 256; d2.cStride = (size_t)Nd * 256; d2.cKind = 1;
      d2.M = cr; d2.K = 768; d2.relu = 1;
      d2.aggM = aggM; d2.aggS = aggS; d2.invdeg = invdeg;
      d2.aggStride = (size_t)CH * 256; d2.invStride = CH;
      GemmDesc d1{};
      d1.A = featS + (size_t)c0 * 256; d1.lda = 256; d1.aStride = 0; d1.aKind = 1;
      d1.Wt = wt_fc1[layer]; d1.wStride = (size_t)256 * 128; d1.bias = lb[0]; d1.biasStride = 128;
      d1.C = inp + 128 + (size_t)c0 * 256; d1.ldc = 256; d1.cStride = (size_t)Nd * 256; d1.cKind = 1;
      d1.M = cr; d1.K = 256; d1.relu = 1;
      d1.aggM = aggM; d1.aggS = aggS; d1.invdeg = invdeg; d1.aggStride = 0; d1.invStride = 0;
      gemm_mfma<<<dim3((cr + 127) / 128, 3, 2), 256, 0, stream>>>(d2, d1);
    }
    // fc3 -> z (fp32)
    {
      GemmDesc d3{};
      d3.A = inp; d3.lda = 256; d3.aStride = (size_t)N1 * 0 + (size_t)Nd * 256; d3.aKind = 1;
      d3.Wt = wt_fc3[layer]; d3.wStride = (size_t)256 * 128; d3.bias = lb[2]; d3.biasStride = 128;
      d3.C = z; d3.ldc = 128; d3.cStride = (size_t)Nd * 128; d3.cKind = 0;
      d3.M = Nd; d3.K = 256; d3.relu = 0;
      d3.aggM = aggM; d3.aggS = aggS; d3.invdeg = invdeg; d3.aggStride = 0; d3.invStride = 0;
      gemm_mfma<<<dim3((Nd + 127) / 128, 3, 1), 256, 0, stream>>>(d3, dz);
    }

    hipMemsetAsync(wsum, 0, 3 * sizeof(float), stream);
    attn_mfma<<<dim3((Nd + 127) / 128, 3), 256, 0, stream>>>(z, wt_attn, attn_b1, attn_w2, Nd, wsum);
    beta_kernel<<<1, 1, 0, stream>>>(wsum, 1.0f / (float)Nd, beta);

    if (layer == 0) {
      combine1_kernel<<<N1, 256, 0, stream>>>(z, beta, tss, rs, src_nid1, N1, feat1);
    } else {
      combine2_pred<<<N2, 128, 0, stream>>>(z, beta, N2, pred_w, pred_b, out);
    }
  }
}